// Round 4
// baseline (415.293 us; speedup 1.0000x reference)
//
#include <hip/hip_runtime.h>

typedef unsigned short u16;
typedef unsigned int u32;
typedef __bf16 bf16x8 __attribute__((ext_vector_type(8)));
typedef float f32x4 __attribute__((ext_vector_type(4)));
typedef u16 u16x4 __attribute__((ext_vector_type(4)));
typedef u16 u16x8 __attribute__((ext_vector_type(8)));

#define MFMA16x16x32(a, b, c) __builtin_amdgcn_mfma_f32_16x16x32_bf16((a), (b), (c), 0, 0, 0)

static constexpr int kB = 4;
static constexpr int kC = 256;
static constexpr int kN = 4096;     // H*W
static constexpr int kHeads = 4;    // per batch
static constexpr int kD = 64;       // head dim
static constexpr int kSplit = 4;    // attn is reg-capped, not grid-capped; 4 halves combine traffic
static constexpr float kScale = 0.35355339059327373f;   // 64^-0.25 (K side)
static constexpr float kScaleQ = 0.51006971545f;        // 64^-0.25 * log2(e) (Q side, r15: exp->exp2)

__device__ __forceinline__ u16 f2bf(float f) {
  union { float f; u32 i; } v; v.f = f;
  return (u16)((v.i + 0x7fffu + ((v.i >> 16) & 1u)) >> 16);
}
__device__ __forceinline__ bf16x8 ldb8(const u16* p) {
  return *reinterpret_cast<const bf16x8*>(p);
}

// ---------------------------------------------------------------------------
// fp32 -> bf16 weight conversion (grid-stride).
// ---------------------------------------------------------------------------
__global__ void convert_bf16(const float* __restrict__ in, u16* __restrict__ out,
                             int n) {
  for (int i = blockIdx.x * blockDim.x + threadIdx.x; i < n;
       i += gridDim.x * blockDim.x)
    out[i] = f2bf(in[i]);
}

// ---------------------------------------------------------------------------
// GroupNorm (validated r4). Writes bf16 transposed xnT[b][t][c].
// ---------------------------------------------------------------------------
__global__ __launch_bounds__(1024) void gn_kernel(const float* __restrict__ x,
                                                  const float* __restrict__ gnw,
                                                  const float* __restrict__ gnb,
                                                  u16* __restrict__ xnT) {
  const int g = blockIdx.x, b = blockIdx.y;
  const int tid = threadIdx.x;
  const float* xb = x + b * (kC * kN) + g * 8 * kN;
  float vals[4][8];
  float s = 0.f, ss = 0.f;
#pragma unroll
  for (int kk = 0; kk < 4; ++kk) {
    const int t = tid + kk * 1024;
#pragma unroll
    for (int c = 0; c < 8; ++c) {
      const float v_ = xb[c * kN + t];
      vals[kk][c] = v_;
      s += v_; ss += v_ * v_;
    }
  }
#pragma unroll
  for (int off = 32; off > 0; off >>= 1) {
    s += __shfl_down(s, off);
    ss += __shfl_down(ss, off);
  }
  __shared__ float rbuf[32];
  const int wid = tid >> 6, lane = tid & 63;
  if (lane == 0) { rbuf[wid] = s; rbuf[16 + wid] = ss; }
  __syncthreads();
  if (tid < 64) {
    float s2 = (lane < 16) ? rbuf[lane] : 0.f;
    float ss2 = (lane < 16) ? rbuf[16 + lane] : 0.f;
#pragma unroll
    for (int off = 8; off > 0; off >>= 1) {
      s2 += __shfl_down(s2, off);
      ss2 += __shfl_down(ss2, off);
    }
    if (lane == 0) { rbuf[0] = s2; rbuf[1] = ss2; }
  }
  __syncthreads();
  const float inv_n = 1.f / 32768.f;
  const float mu = rbuf[0] * inv_n;
  const float var = rbuf[1] * inv_n - mu * mu;
  const float rs = rsqrtf(var + 1e-5f);
  float wv[8], bv[8];
#pragma unroll
  for (int c = 0; c < 8; ++c) {
    const float wgt = gnw[g * 8 + c] * rs;
    wv[c] = wgt;
    bv[c] = gnb[g * 8 + c] - mu * wgt;
  }
  u16* ob = xnT + b * (kN * kC) + g * 8;
#pragma unroll
  for (int kk = 0; kk < 4; ++kk) {
    const int t = tid + kk * 1024;
    u16x8 pk;
#pragma unroll
    for (int c = 0; c < 8; ++c) pk[c] = f2bf(vals[kk][c] * wv[c] + bv[c]);
    *reinterpret_cast<u16x8*>(ob + t * kC) = pk;
  }
}

// ---------------------------------------------------------------------------
// QKV GEMM (validated r4). Epilogue: qT/kT[bh][t][64] pre-scaled.
// r14: V stored PERMUTED within each 32-column block: stored index
// 2c <-> s=c, 2c+1 <-> s=c+16. Matches attn's packed-P LDS ordering
// (MFMA k-order is summation order -> exact as long as P and V agree).
// r15: Q side additionally folds log2(e) so attn uses exp2 directly.
// ---------------------------------------------------------------------------
__global__ __launch_bounds__(256) void qkv_gemm(const u16* __restrict__ qkvw,
                                                const float* __restrict__ qkvb,
                                                const u16* __restrict__ xnT,
                                                u16* __restrict__ qt,
                                                u16* __restrict__ kt,
                                                u16* __restrict__ vv) {
  const int nblk = blockIdx.x, mblk = blockIdx.y, b = blockIdx.z;
  const int tid = threadIdx.x;
  const int w = tid >> 6, l = tid & 63, quad = l >> 4, col = l & 15;
  const int m0 = mblk * 64 + w * 16;
  const int n0 = nblk * 64;
  const u16* xb = xnT + b * (kN * kC);
  f32x4 acc[4] = {{0,0,0,0},{0,0,0,0},{0,0,0,0},{0,0,0,0}};
  const u16* ap = qkvw + (m0 + col) * kC + quad * 8;
  const u16* bp = xb + (n0 + col) * kC + quad * 8;
#pragma unroll
  for (int ks = 0; ks < 8; ++ks) {
    const bf16x8 af = ldb8(ap + ks * 32);
#pragma unroll
    for (int nt = 0; nt < 4; ++nt) {
      const bf16x8 bfr = ldb8(bp + nt * (16 * kC) + ks * 32);
      acc[nt] = MFMA16x16x32(af, bfr, acc[nt]);
    }
  }
  const int o_base = m0 + quad * 4;
  const int head = o_base / 192;
  const int rr = o_base % 192;
  const int bh = b * kHeads + head;
  const int seg = rr >> 6;
  const int c0 = rr & 63;
  float bias[4];
#pragma unroll
  for (int r = 0; r < 4; ++r) bias[r] = qkvb[o_base + r];
  const float sc = (seg == 0) ? kScaleQ : kScale;
#pragma unroll
  for (int nt = 0; nt < 4; ++nt) {
    const int t = n0 + nt * 16 + col;
    if (seg == 2) {
      // permuted position within the 32-block (see header comment)
      const int tp = n0 + (nt >> 1) * 32 + 2 * col + (nt & 1);
#pragma unroll
      for (int r = 0; r < 4; ++r)
        vv[bh * (kD * kN) + (c0 + r) * kN + tp] = f2bf(acc[nt][r] + bias[r]);
    } else {
      u16* dst = (seg == 0 ? qt : kt) + bh * (kN * kD) + t * kD + c0;
      u16x4 pk;
#pragma unroll
      for (int r = 0; r < 4; ++r) pk[r] = f2bf((acc[nt][r] + bias[r]) * sc);
      *reinterpret_cast<u16x4*>(dst) = pk;
    }
  }
}

// ---------------------------------------------------------------------------
// Flash attention, linear split form, 32 Q-rows/wave (2 Q-tiles).
// r14: P written to LDS as u32 pairs (p_c, p_{c+16}) via one v_perm_b32.
// r15: exp2f with log2e folded into Q scale (kept).
// r16 POST-MORTEM: forcing (256,3) on the 4-tile body -> accvgpr-shuffle
// explosion (VALUBusy 25->38), 140->170us. Body needs >168 regs.
// r17 POST-MORTEM: reg prefetch+rotation -> +230 VALU cyc/iter of address
// recompute (VALUBusy 44), 149us. Source-level scheduling = VALU bloat.
// r18: change the BODY, not the cap. 2 Q-tiles/wave (32 rows): oacc 64->32,
// lacc 16->8, qf 16->8 regs => natural footprint ~124 < 128 => 4 waves/SIMD
// fits WITHOUT fighting the allocator. Grid tblk 16->32; pbuf halves to 9KB.
// K/V refetch doubles (HBM at 12%, headroom). launch_bounds(256,4) is now
// at/above natural need (opposite of r16).
// ---------------------------------------------------------------------------
__global__ __launch_bounds__(256, 4) void attn_split(const u16* __restrict__ qt,
                                                     const u16* __restrict__ kt,
                                                     const u16* __restrict__ vv,
                                                     float* __restrict__ pO,
                                                     float* __restrict__ pl) {
  const int tblk = blockIdx.x, bh = blockIdx.y, z = blockIdx.z;
  const int tid = threadIdx.x;
  const int w = tid >> 6, l = tid & 63, quad = l >> 4, col = l & 15;
  const int t0 = tblk * 128 + w * 32;
  const u16* qb = qt + bh * (kN * kD);
  const u16* kb = kt + bh * (kN * kD);
  const u16* vb = vv + bh * (kD * kN);
  bf16x8 qf[2][2];
#pragma unroll
  for (int ti = 0; ti < 2; ++ti) {
    qf[ti][0] = ldb8(qb + (t0 + ti * 16 + col) * kD + quad * 8);
    qf[ti][1] = ldb8(qb + (t0 + ti * 16 + col) * kD + 32 + quad * 8);
  }
  u16x8 ones_u;
#pragma unroll
  for (int i = 0; i < 8; ++i) ones_u[i] = 0x3f80;  // bf16 1.0
  const bf16x8 onesf = *reinterpret_cast<bf16x8*>(&ones_u);
  f32x4 oacc[2][4];
  f32x4 lacc[2];
#pragma unroll
  for (int ti = 0; ti < 2; ++ti) {
    lacc[ti] = f32x4{0, 0, 0, 0};
#pragma unroll
    for (int ct = 0; ct < 4; ++ct) oacc[ti][ct] = f32x4{0, 0, 0, 0};
  }
  __shared__ __align__(16) u16 pbuf[4][2][16][36];  // 9216 B, row stride 72 B
  const int s_beg = z * (kN / kSplit);

  for (int ii = 0; ii < kN / kSplit; ii += 32) {
    const int s0 = s_beg + ii;
    const u16* kr = kb + s0 * kD + quad * 8;
    const bf16x8 k00 = ldb8(kr + col * kD);
    const bf16x8 k01 = ldb8(kr + col * kD + 32);
    const bf16x8 k10 = ldb8(kr + (col + 16) * kD);
    const bf16x8 k11 = ldb8(kr + (col + 16) * kD + 32);
    u16(*pw)[16][36] = pbuf[w];
#pragma unroll
    for (int ti = 0; ti < 2; ++ti) {
      f32x4 sa0 = {0, 0, 0, 0}, sa1 = {0, 0, 0, 0};
      sa0 = MFMA16x16x32(qf[ti][0], k00, sa0);
      sa0 = MFMA16x16x32(qf[ti][1], k01, sa0);
      sa1 = MFMA16x16x32(qf[ti][0], k10, sa1);
      sa1 = MFMA16x16x32(qf[ti][1], k11, sa1);
#pragma unroll
      for (int r = 0; r < 4; ++r) {
        const u32 e0 = __float_as_uint(exp2f(sa0[r]));
        const u32 e1 = __float_as_uint(exp2f(sa1[r]));
        // one v_perm: low16 = bf16_rtz(e0) [s=col], high16 = bf16_rtz(e1) [s=col+16]
        const u32 pk = __builtin_amdgcn_perm(e1, e0, 0x07060302u);
        *reinterpret_cast<u32*>(&pw[ti][quad * 4 + r][2 * col]) = pk;
      }
    }
    // V fragment loads issued here: latency overlaps the DS drain below,
    // short live range keeps register pressure down.
    const u16* vr = vb + s0 + quad * 8;
    bf16x8 vf[4];
#pragma unroll
    for (int ct = 0; ct < 4; ++ct) vf[ct] = ldb8(vr + (ct * 16 + col) * kN);
    // wave-private LDS region: drain writes, then read A-layout fragments.
    // DS is in-order per wave, so next-iter writes cannot bypass these reads.
    asm volatile("s_waitcnt lgkmcnt(0)" ::: "memory");
#pragma unroll
    for (int ti = 0; ti < 2; ++ti) {
      const bf16x8 pf = ldb8(&pw[ti][col][quad * 8]);
#pragma unroll
      for (int ct = 0; ct < 4; ++ct)
        oacc[ti][ct] = MFMA16x16x32(pf, vf[ct], oacc[ti][ct]);
      lacc[ti] = MFMA16x16x32(pf, onesf, lacc[ti]);
    }
  }
  float* po = pO + (size_t)(z * 16 + bh) * kN * kD;
  float* plp = pl + (size_t)(z * 16 + bh) * kN;
#pragma unroll
  for (int ti = 0; ti < 2; ++ti)
#pragma unroll
    for (int r = 0; r < 4; ++r) {
      const int t = t0 + ti * 16 + quad * 4 + r;
#pragma unroll
      for (int ct = 0; ct < 4; ++ct)
        po[(size_t)t * kD + ct * 16 + col] = oacc[ti][ct][r];
      if (col == 0) plp[t] = lacc[ti][r];
    }
}

// ---------------------------------------------------------------------------
// Combine 4 split partials: O = sum_z O_z / sum_z l_z -> ht[b][t][c] bf16.
// ---------------------------------------------------------------------------
__global__ __launch_bounds__(256) void attn_combine(const float* __restrict__ pO,
                                                    const float* __restrict__ pl,
                                                    u16* __restrict__ ht) {
  const int idx = blockIdx.x * 256 + threadIdx.x;   // 16bh * 4096t * 16chunks
  const int c0 = (idx & 15) * 4;
  const int t = (idx >> 4) & (kN - 1);
  const int bh = idx >> 16;
  f32x4 acc = {0, 0, 0, 0};
  float lsum = 0.f;
#pragma unroll
  for (int z = 0; z < kSplit; ++z) {
    const size_t base = ((size_t)(z * 16 + bh) * kN + t);
    acc += *reinterpret_cast<const f32x4*>(pO + base * kD + c0);
    lsum += pl[base];
  }
  const float inv = 1.f / lsum;
  u16x4 pk;
#pragma unroll
  for (int i = 0; i < 4; ++i) pk[i] = f2bf(acc[i] * inv);
  const int b = bh >> 2, head = bh & 3;
  *reinterpret_cast<u16x4*>(ht + (size_t)b * (kN * kC) + (size_t)t * kC +
                            head * kD + c0) = pk;
}

// ---------------------------------------------------------------------------
// Proj GEMM + bias + residual: out fp32 (B,C,H,W). Validated r6.
// ---------------------------------------------------------------------------
__global__ __launch_bounds__(256) void proj_kernel(const u16* __restrict__ projw,
                                                   const float* __restrict__ projb,
                                                   const u16* __restrict__ ht,
                                                   const float* __restrict__ x,
                                                   float* __restrict__ out) {
  const int nblk = blockIdx.x, mblk = blockIdx.y, b = blockIdx.z;
  const int tid = threadIdx.x;
  const int w = tid >> 6, l = tid & 63, quad = l >> 4, col = l & 15;
  const int m0 = mblk * 64 + w * 16;
  const int n0 = nblk * 64;
  const u16* hb = ht + b * (kN * kC);
  f32x4 acc[4] = {{0,0,0,0},{0,0,0,0},{0,0,0,0},{0,0,0,0}};
  const u16* ap = projw + (m0 + col) * kC + quad * 8;
  const u16* bp = hb + (n0 + col) * kC + quad * 8;
#pragma unroll
  for (int ks = 0; ks < 8; ++ks) {
    const bf16x8 af = ldb8(ap + ks * 32);
#pragma unroll
    for (int nt = 0; nt < 4; ++nt) {
      const bf16x8 bfr = ldb8(bp + nt * (16 * kC) + ks * 32);
      acc[nt] = MFMA16x16x32(af, bfr, acc[nt]);
    }
  }
#pragma unroll
  for (int nt = 0; nt < 4; ++nt) {
    const int t = n0 + nt * 16 + col;
#pragma unroll
    for (int r = 0; r < 4; ++r) {
      const int o = m0 + quad * 4 + r;
      const int idx = b * (kC * kN) + o * kN + t;
      out[idx] = acc[nt][r] + projb[o] + x[idx];
    }
  }
}

extern "C" void kernel_launch(void* const* d_in, const int* in_sizes, int n_in,
                              void* d_out, int out_size, void* d_ws, size_t ws_size,
                              hipStream_t stream) {
  const float* x = (const float*)d_in[0];
  const float* gnw = (const float*)d_in[1];
  const float* gnb = (const float*)d_in[2];
  const float* qkvw_f = (const float*)d_in[3];
  const float* qkvb = (const float*)d_in[4];
  const float* projw_f = (const float*)d_in[5];
  const float* projb = (const float*)d_in[6];
  float* out = (float*)d_out;

  char* ws = (char*)d_ws;
  u16* xnT = (u16*)(ws);                      // 8 MiB
  u16* qt = (u16*)(ws + (8u << 20));          // 8 MiB
  u16* kt = (u16*)(ws + (16u << 20));         // 8 MiB
  u16* vv = (u16*)(ws + (24u << 20));         // 8 MiB
  u16* ht = (u16*)(ws + (32u << 20));         // 8 MiB
  u16* qkvw = (u16*)(ws + (40u << 20));       // 384 KiB
  u16* projw = (u16*)(ws + (41u << 20));      // 128 KiB
  float* pO = (float*)(ws + (48u << 20));     // 64 MiB (4 splits)
  float* pl = (float*)(ws + (112u << 20));    // 1 MiB

  convert_bf16<<<dim3(192), dim3(256), 0, stream>>>(qkvw_f, qkvw, 768 * kC);
  convert_bf16<<<dim3(64), dim3(256), 0, stream>>>(projw_f, projw, kC * kC);
  gn_kernel<<<dim3(32, 4), dim3(1024), 0, stream>>>(x, gnw, gnb, xnT);
  qkv_gemm<<<dim3(64, 12, 4), dim3(256), 0, stream>>>(qkvw, qkvb, xnT, qt, kt, vv);
  attn_split<<<dim3(32, 16, kSplit), dim3(256), 0, stream>>>(qt, kt, vv, pO, pl);
  attn_combine<<<dim3(4096), dim3(256), 0, stream>>>(pO, pl, ht);
  proj_kernel<<<dim3(64, 4, 4), dim3(256), 0, stream>>>(projw, projb, ht, x, out);
}

// Round 5
// 309.072 us; speedup vs baseline: 1.3437x; 1.3437x over previous
//
#include <hip/hip_runtime.h>

typedef unsigned short u16;
typedef unsigned int u32;
typedef __bf16 bf16x8 __attribute__((ext_vector_type(8)));
typedef float f32x4 __attribute__((ext_vector_type(4)));
typedef u16 u16x4 __attribute__((ext_vector_type(4)));
typedef u16 u16x8 __attribute__((ext_vector_type(8)));

#define MFMA16x16x32(a, b, c) __builtin_amdgcn_mfma_f32_16x16x32_bf16((a), (b), (c), 0, 0, 0)

static constexpr int kB = 4;
static constexpr int kC = 256;
static constexpr int kN = 4096;     // H*W
static constexpr int kHeads = 4;    // per batch
static constexpr int kD = 64;       // head dim
static constexpr int kSplit = 4;
static constexpr float kScale = 0.35355339059327373f;   // 64^-0.25 (K side)
static constexpr float kScaleQ = 0.51006971545f;        // 64^-0.25 * log2(e) (Q side)

__device__ __forceinline__ u16 f2bf(float f) {
  union { float f; u32 i; } v; v.f = f;
  return (u16)((v.i + 0x7fffu + ((v.i >> 16) & 1u)) >> 16);
}
__device__ __forceinline__ bf16x8 ldb8(const u16* p) {
  return *reinterpret_cast<const bf16x8*>(p);
}

// ---------------------------------------------------------------------------
// fp32 -> bf16 weight conversion (grid-stride).
// ---------------------------------------------------------------------------
__global__ void convert_bf16(const float* __restrict__ in, u16* __restrict__ out,
                             int n) {
  for (int i = blockIdx.x * blockDim.x + threadIdx.x; i < n;
       i += gridDim.x * blockDim.x)
    out[i] = f2bf(in[i]);
}

// ---------------------------------------------------------------------------
// GroupNorm (validated r4). Writes bf16 transposed xnT[b][t][c].
// ---------------------------------------------------------------------------
__global__ __launch_bounds__(1024) void gn_kernel(const float* __restrict__ x,
                                                  const float* __restrict__ gnw,
                                                  const float* __restrict__ gnb,
                                                  u16* __restrict__ xnT) {
  const int g = blockIdx.x, b = blockIdx.y;
  const int tid = threadIdx.x;
  const float* xb = x + b * (kC * kN) + g * 8 * kN;
  float vals[4][8];
  float s = 0.f, ss = 0.f;
#pragma unroll
  for (int kk = 0; kk < 4; ++kk) {
    const int t = tid + kk * 1024;
#pragma unroll
    for (int c = 0; c < 8; ++c) {
      const float v_ = xb[c * kN + t];
      vals[kk][c] = v_;
      s += v_; ss += v_ * v_;
    }
  }
#pragma unroll
  for (int off = 32; off > 0; off >>= 1) {
    s += __shfl_down(s, off);
    ss += __shfl_down(ss, off);
  }
  __shared__ float rbuf[32];
  const int wid = tid >> 6, lane = tid & 63;
  if (lane == 0) { rbuf[wid] = s; rbuf[16 + wid] = ss; }
  __syncthreads();
  if (tid < 64) {
    float s2 = (lane < 16) ? rbuf[lane] : 0.f;
    float ss2 = (lane < 16) ? rbuf[16 + lane] : 0.f;
#pragma unroll
    for (int off = 8; off > 0; off >>= 1) {
      s2 += __shfl_down(s2, off);
      ss2 += __shfl_down(ss2, off);
    }
    if (lane == 0) { rbuf[0] = s2; rbuf[1] = ss2; }
  }
  __syncthreads();
  const float inv_n = 1.f / 32768.f;
  const float mu = rbuf[0] * inv_n;
  const float var = rbuf[1] * inv_n - mu * mu;
  const float rs = rsqrtf(var + 1e-5f);
  float wv[8], bv[8];
#pragma unroll
  for (int c = 0; c < 8; ++c) {
    const float wgt = gnw[g * 8 + c] * rs;
    wv[c] = wgt;
    bv[c] = gnb[g * 8 + c] - mu * wgt;
  }
  u16* ob = xnT + b * (kN * kC) + g * 8;
#pragma unroll
  for (int kk = 0; kk < 4; ++kk) {
    const int t = tid + kk * 1024;
    u16x8 pk;
#pragma unroll
    for (int c = 0; c < 8; ++c) pk[c] = f2bf(vals[kk][c] * wv[c] + bv[c]);
    *reinterpret_cast<u16x8*>(ob + t * kC) = pk;
  }
}

// ---------------------------------------------------------------------------
// QKV GEMM. Epilogue: qT/kT[bh][t][64] pre-scaled (Q also folds log2e).
// r19: V stored with the SWAPPED-QK^T slot permutation. attn's in-register
// P fragment has k-slot order: slot j (at quad q) holds actual s =
//   j<4 ? 4q+j : 16+4q+(j-4)   (within each 32-s block).
// V stored index m within the 32-block must hold actual s per the same map:
//   m = 8*(s&15>>2) + 4*(s>>4) + (s&3)
// With s_in = (nt&1)*16 + col:  m = 8*(col>>2) + 4*(nt&1) + (col&3).
// MFMA contracts slot-by-slot, so P/V agreement keeps the product exact.
// ---------------------------------------------------------------------------
__global__ __launch_bounds__(256) void qkv_gemm(const u16* __restrict__ qkvw,
                                                const float* __restrict__ qkvb,
                                                const u16* __restrict__ xnT,
                                                u16* __restrict__ qt,
                                                u16* __restrict__ kt,
                                                u16* __restrict__ vv) {
  const int nblk = blockIdx.x, mblk = blockIdx.y, b = blockIdx.z;
  const int tid = threadIdx.x;
  const int w = tid >> 6, l = tid & 63, quad = l >> 4, col = l & 15;
  const int m0 = mblk * 64 + w * 16;
  const int n0 = nblk * 64;
  const u16* xb = xnT + b * (kN * kC);
  f32x4 acc[4] = {{0,0,0,0},{0,0,0,0},{0,0,0,0},{0,0,0,0}};
  const u16* ap = qkvw + (m0 + col) * kC + quad * 8;
  const u16* bp = xb + (n0 + col) * kC + quad * 8;
#pragma unroll
  for (int ks = 0; ks < 8; ++ks) {
    const bf16x8 af = ldb8(ap + ks * 32);
#pragma unroll
    for (int nt = 0; nt < 4; ++nt) {
      const bf16x8 bfr = ldb8(bp + nt * (16 * kC) + ks * 32);
      acc[nt] = MFMA16x16x32(af, bfr, acc[nt]);
    }
  }
  const int o_base = m0 + quad * 4;
  const int head = o_base / 192;
  const int rr = o_base % 192;
  const int bh = b * kHeads + head;
  const int seg = rr >> 6;
  const int c0 = rr & 63;
  float bias[4];
#pragma unroll
  for (int r = 0; r < 4; ++r) bias[r] = qkvb[o_base + r];
  const float sc = (seg == 0) ? kScaleQ : kScale;
#pragma unroll
  for (int nt = 0; nt < 4; ++nt) {
    const int t = n0 + nt * 16 + col;
    if (seg == 2) {
      // r19 permuted position within the 32-block (see header comment)
      const int tp = n0 + (nt >> 1) * 32 + 8 * (col >> 2) + 4 * (nt & 1) + (col & 3);
#pragma unroll
      for (int r = 0; r < 4; ++r)
        vv[bh * (kD * kN) + (c0 + r) * kN + tp] = f2bf(acc[nt][r] + bias[r]);
    } else {
      u16* dst = (seg == 0 ? qt : kt) + bh * (kN * kD) + t * kD + c0;
      u16x4 pk;
#pragma unroll
      for (int r = 0; r < 4; ++r) pk[r] = f2bf((acc[nt][r] + bias[r]) * sc);
      *reinterpret_cast<u16x4*>(dst) = pk;
    }
  }
}

// ---------------------------------------------------------------------------
// Flash attention, linear split form, 64 Q-rows/wave (4 Q-tiles).
// r16-r18 POST-MORTEMS: occupancy is not the lever (forcing regs down ->
// accvgpr shuffles; manual prefetch -> VALU addr bloat; halving tile ->
// latency chain dominates). The chain itself (QK -> exp -> LDS write ->
// lgkm drain -> LDS read -> PV) is the bottleneck.
// r19: SWAPPED QK^T kills the LDS round-trip. mfma(K,Q) is legal (A/B frags
// have identical per-lane layout) and yields S^T: lane(quad,col) holds
// P[q=col][s = s0+quad*4+r] (sa0) and s0+16+quad*4+r (sa1) -- exactly a PV
// A-fragment if V's k-slots are stored in the matching order (done in
// qkv_gemm). P never leaves registers: no pbuf, no drain asm (which also
// unblocks compiler cross-iteration load hoisting). Output fragment mapping
// is unchanged -> epilogue identical.
// ---------------------------------------------------------------------------
__global__ __launch_bounds__(256, 2) void attn_split(const u16* __restrict__ qt,
                                                     const u16* __restrict__ kt,
                                                     const u16* __restrict__ vv,
                                                     float* __restrict__ pO,
                                                     float* __restrict__ pl) {
  const int tblk = blockIdx.x, bh = blockIdx.y, z = blockIdx.z;
  const int tid = threadIdx.x;
  const int w = tid >> 6, l = tid & 63, quad = l >> 4, col = l & 15;
  const int t0 = tblk * 256 + w * 64;
  const u16* qb = qt + bh * (kN * kD);
  const u16* kb = kt + bh * (kN * kD);
  const u16* vb = vv + bh * (kD * kN);
  bf16x8 qf[4][2];
#pragma unroll
  for (int ti = 0; ti < 4; ++ti) {
    qf[ti][0] = ldb8(qb + (t0 + ti * 16 + col) * kD + quad * 8);
    qf[ti][1] = ldb8(qb + (t0 + ti * 16 + col) * kD + 32 + quad * 8);
  }
  u16x8 ones_u;
#pragma unroll
  for (int i = 0; i < 8; ++i) ones_u[i] = 0x3f80;  // bf16 1.0
  const bf16x8 onesf = *reinterpret_cast<bf16x8*>(&ones_u);
  f32x4 oacc[4][4];
  f32x4 lacc[4];
#pragma unroll
  for (int ti = 0; ti < 4; ++ti) {
    lacc[ti] = f32x4{0, 0, 0, 0};
#pragma unroll
    for (int ct = 0; ct < 4; ++ct) oacc[ti][ct] = f32x4{0, 0, 0, 0};
  }
  const int s_beg = z * (kN / kSplit);

  for (int ii = 0; ii < kN / kSplit; ii += 32) {
    const int s0 = s_beg + ii;
    const u16* kr = kb + s0 * kD + quad * 8;
    const bf16x8 k00 = ldb8(kr + col * kD);          // A rows s0+0..15, d 0..31
    const bf16x8 k01 = ldb8(kr + col * kD + 32);     // A rows s0+0..15, d 32..63
    const bf16x8 k10 = ldb8(kr + (col + 16) * kD);   // A rows s0+16..31
    const bf16x8 k11 = ldb8(kr + (col + 16) * kD + 32);
    const u16* vr = vb + s0 + quad * 8;
    bf16x8 vf[4];
#pragma unroll
    for (int ct = 0; ct < 4; ++ct) vf[ct] = ldb8(vr + (ct * 16 + col) * kN);
#pragma unroll
    for (int ti = 0; ti < 4; ++ti) {
      // swapped: A = K (rows = s), B = Q (cols = q)
      f32x4 sa0 = {0, 0, 0, 0}, sa1 = {0, 0, 0, 0};
      sa0 = MFMA16x16x32(k00, qf[ti][0], sa0);
      sa0 = MFMA16x16x32(k01, qf[ti][1], sa0);
      sa1 = MFMA16x16x32(k10, qf[ti][0], sa1);
      sa1 = MFMA16x16x32(k11, qf[ti][1], sa1);
      // lane holds P[q=col][s]: sa0[r] -> s=s0+quad*4+r, sa1[r] -> +16.
      // Pack into PV A-frag: slots {sa0[0..3], sa1[0..3]} (V stored to match).
      const u32 e00 = __float_as_uint(exp2f(sa0[0]));
      const u32 e01 = __float_as_uint(exp2f(sa0[1]));
      const u32 e02 = __float_as_uint(exp2f(sa0[2]));
      const u32 e03 = __float_as_uint(exp2f(sa0[3]));
      const u32 e10 = __float_as_uint(exp2f(sa1[0]));
      const u32 e11 = __float_as_uint(exp2f(sa1[1]));
      const u32 e12 = __float_as_uint(exp2f(sa1[2]));
      const u32 e13 = __float_as_uint(exp2f(sa1[3]));
      union { u32 wd[4]; bf16x8 v; } pa;
      // perm(a,b,0x07060302): lo16 = bf16_rtz(b), hi16 = bf16_rtz(a)
      pa.wd[0] = __builtin_amdgcn_perm(e01, e00, 0x07060302u);
      pa.wd[1] = __builtin_amdgcn_perm(e03, e02, 0x07060302u);
      pa.wd[2] = __builtin_amdgcn_perm(e11, e10, 0x07060302u);
      pa.wd[3] = __builtin_amdgcn_perm(e13, e12, 0x07060302u);
#pragma unroll
      for (int ct = 0; ct < 4; ++ct)
        oacc[ti][ct] = MFMA16x16x32(pa.v, vf[ct], oacc[ti][ct]);
      lacc[ti] = MFMA16x16x32(pa.v, onesf, lacc[ti]);
    }
  }
  float* po = pO + (size_t)(z * 16 + bh) * kN * kD;
  float* plp = pl + (size_t)(z * 16 + bh) * kN;
#pragma unroll
  for (int ti = 0; ti < 4; ++ti)
#pragma unroll
    for (int r = 0; r < 4; ++r) {
      const int t = t0 + ti * 16 + quad * 4 + r;
#pragma unroll
      for (int ct = 0; ct < 4; ++ct)
        po[(size_t)t * kD + ct * 16 + col] = oacc[ti][ct][r];
      if (col == 0) plp[t] = lacc[ti][r];
    }
}

// ---------------------------------------------------------------------------
// Combine 4 split partials: O = sum_z O_z / sum_z l_z -> ht[b][t][c] bf16.
// ---------------------------------------------------------------------------
__global__ __launch_bounds__(256) void attn_combine(const float* __restrict__ pO,
                                                    const float* __restrict__ pl,
                                                    u16* __restrict__ ht) {
  const int idx = blockIdx.x * 256 + threadIdx.x;   // 16bh * 4096t * 16chunks
  const int c0 = (idx & 15) * 4;
  const int t = (idx >> 4) & (kN - 1);
  const int bh = idx >> 16;
  f32x4 acc = {0, 0, 0, 0};
  float lsum = 0.f;
#pragma unroll
  for (int z = 0; z < kSplit; ++z) {
    const size_t base = ((size_t)(z * 16 + bh) * kN + t);
    acc += *reinterpret_cast<const f32x4*>(pO + base * kD + c0);
    lsum += pl[base];
  }
  const float inv = 1.f / lsum;
  u16x4 pk;
#pragma unroll
  for (int i = 0; i < 4; ++i) pk[i] = f2bf(acc[i] * inv);
  const int b = bh >> 2, head = bh & 3;
  *reinterpret_cast<u16x4*>(ht + (size_t)b * (kN * kC) + (size_t)t * kC +
                            head * kD + c0) = pk;
}

// ---------------------------------------------------------------------------
// Proj GEMM + bias + residual: out fp32 (B,C,H,W). Validated r6.
// ---------------------------------------------------------------------------
__global__ __launch_bounds__(256) void proj_kernel(const u16* __restrict__ projw,
                                                   const float* __restrict__ projb,
                                                   const u16* __restrict__ ht,
                                                   const float* __restrict__ x,
                                                   float* __restrict__ out) {
  const int nblk = blockIdx.x, mblk = blockIdx.y, b = blockIdx.z;
  const int tid = threadIdx.x;
  const int w = tid >> 6, l = tid & 63, quad = l >> 4, col = l & 15;
  const int m0 = mblk * 64 + w * 16;
  const int n0 = nblk * 64;
  const u16* hb = ht + b * (kN * kC);
  f32x4 acc[4] = {{0,0,0,0},{0,0,0,0},{0,0,0,0},{0,0,0,0}};
  const u16* ap = projw + (m0 + col) * kC + quad * 8;
  const u16* bp = hb + (n0 + col) * kC + quad * 8;
#pragma unroll
  for (int ks = 0; ks < 8; ++ks) {
    const bf16x8 af = ldb8(ap + ks * 32);
#pragma unroll
    for (int nt = 0; nt < 4; ++nt) {
      const bf16x8 bfr = ldb8(bp + nt * (16 * kC) + ks * 32);
      acc[nt] = MFMA16x16x32(af, bfr, acc[nt]);
    }
  }
#pragma unroll
  for (int nt = 0; nt < 4; ++nt) {
    const int t = n0 + nt * 16 + col;
#pragma unroll
    for (int r = 0; r < 4; ++r) {
      const int o = m0 + quad * 4 + r;
      const int idx = b * (kC * kN) + o * kN + t;
      out[idx] = acc[nt][r] + projb[o] + x[idx];
    }
  }
}

extern "C" void kernel_launch(void* const* d_in, const int* in_sizes, int n_in,
                              void* d_out, int out_size, void* d_ws, size_t ws_size,
                              hipStream_t stream) {
  const float* x = (const float*)d_in[0];
  const float* gnw = (const float*)d_in[1];
  const float* gnb = (const float*)d_in[2];
  const float* qkvw_f = (const float*)d_in[3];
  const float* qkvb = (const float*)d_in[4];
  const float* projw_f = (const float*)d_in[5];
  const float* projb = (const float*)d_in[6];
  float* out = (float*)d_out;

  char* ws = (char*)d_ws;
  u16* xnT = (u16*)(ws);                      // 8 MiB
  u16* qt = (u16*)(ws + (8u << 20));          // 8 MiB
  u16* kt = (u16*)(ws + (16u << 20));         // 8 MiB
  u16* vv = (u16*)(ws + (24u << 20));         // 8 MiB
  u16* ht = (u16*)(ws + (32u << 20));         // 8 MiB
  u16* qkvw = (u16*)(ws + (40u << 20));       // 384 KiB
  u16* projw = (u16*)(ws + (41u << 20));      // 128 KiB
  float* pO = (float*)(ws + (48u << 20));     // 64 MiB (4 splits)
  float* pl = (float*)(ws + (112u << 20));    // 1 MiB

  convert_bf16<<<dim3(192), dim3(256), 0, stream>>>(qkvw_f, qkvw, 768 * kC);
  convert_bf16<<<dim3(64), dim3(256), 0, stream>>>(projw_f, projw, kC * kC);
  gn_kernel<<<dim3(32, 4), dim3(1024), 0, stream>>>(x, gnw, gnb, xnT);
  qkv_gemm<<<dim3(64, 12, 4), dim3(256), 0, stream>>>(qkvw, qkvb, xnT, qt, kt, vv);
  attn_split<<<dim3(16, 16, kSplit), dim3(256), 0, stream>>>(qt, kt, vv, pO, pl);
  attn_combine<<<dim3(4096), dim3(256), 0, stream>>>(pO, pl, ht);
  proj_kernel<<<dim3(64, 4, 4), dim3(256), 0, stream>>>(projw, projb, ht, x, out);
}

// Round 6
// 280.209 us; speedup vs baseline: 1.4821x; 1.1030x over previous
//
#include <hip/hip_runtime.h>

typedef unsigned short u16;
typedef unsigned int u32;
typedef __bf16 bf16x8 __attribute__((ext_vector_type(8)));
typedef float f32x4 __attribute__((ext_vector_type(4)));
typedef u16 u16x4 __attribute__((ext_vector_type(4)));
typedef u16 u16x8 __attribute__((ext_vector_type(8)));

#define MFMA16x16x32(a, b, c) __builtin_amdgcn_mfma_f32_16x16x32_bf16((a), (b), (c), 0, 0, 0)

static constexpr int kB = 4;
static constexpr int kC = 256;
static constexpr int kN = 4096;     // H*W
static constexpr int kHeads = 4;    // per batch
static constexpr int kD = 64;       // head dim
static constexpr int kSplit = 4;
static constexpr float kScale = 0.35355339059327373f;   // 64^-0.25 (K side)
static constexpr float kScaleQ = 0.51006971545f;        // 64^-0.25 * log2(e) (Q side)

__device__ __forceinline__ u16 f2bf(float f) {
  union { float f; u32 i; } v; v.f = f;
  return (u16)((v.i + 0x7fffu + ((v.i >> 16) & 1u)) >> 16);
}
__device__ __forceinline__ bf16x8 ldb8(const u16* p) {
  return *reinterpret_cast<const bf16x8*>(p);
}

// ---------------------------------------------------------------------------
// fp32 -> bf16 weight conversion (grid-stride).
// ---------------------------------------------------------------------------
__global__ void convert_bf16(const float* __restrict__ in, u16* __restrict__ out,
                             int n) {
  for (int i = blockIdx.x * blockDim.x + threadIdx.x; i < n;
       i += gridDim.x * blockDim.x)
    out[i] = f2bf(in[i]);
}

// ---------------------------------------------------------------------------
// GroupNorm (validated r4). Writes bf16 transposed xnT[b][t][c].
// ---------------------------------------------------------------------------
__global__ __launch_bounds__(1024) void gn_kernel(const float* __restrict__ x,
                                                  const float* __restrict__ gnw,
                                                  const float* __restrict__ gnb,
                                                  u16* __restrict__ xnT) {
  const int g = blockIdx.x, b = blockIdx.y;
  const int tid = threadIdx.x;
  const float* xb = x + b * (kC * kN) + g * 8 * kN;
  float vals[4][8];
  float s = 0.f, ss = 0.f;
#pragma unroll
  for (int kk = 0; kk < 4; ++kk) {
    const int t = tid + kk * 1024;
#pragma unroll
    for (int c = 0; c < 8; ++c) {
      const float v_ = xb[c * kN + t];
      vals[kk][c] = v_;
      s += v_; ss += v_ * v_;
    }
  }
#pragma unroll
  for (int off = 32; off > 0; off >>= 1) {
    s += __shfl_down(s, off);
    ss += __shfl_down(ss, off);
  }
  __shared__ float rbuf[32];
  const int wid = tid >> 6, lane = tid & 63;
  if (lane == 0) { rbuf[wid] = s; rbuf[16 + wid] = ss; }
  __syncthreads();
  if (tid < 64) {
    float s2 = (lane < 16) ? rbuf[lane] : 0.f;
    float ss2 = (lane < 16) ? rbuf[16 + lane] : 0.f;
#pragma unroll
    for (int off = 8; off > 0; off >>= 1) {
      s2 += __shfl_down(s2, off);
      ss2 += __shfl_down(ss2, off);
    }
    if (lane == 0) { rbuf[0] = s2; rbuf[1] = ss2; }
  }
  __syncthreads();
  const float inv_n = 1.f / 32768.f;
  const float mu = rbuf[0] * inv_n;
  const float var = rbuf[1] * inv_n - mu * mu;
  const float rs = rsqrtf(var + 1e-5f);
  float wv[8], bv[8];
#pragma unroll
  for (int c = 0; c < 8; ++c) {
    const float wgt = gnw[g * 8 + c] * rs;
    wv[c] = wgt;
    bv[c] = gnb[g * 8 + c] - mu * wgt;
  }
  u16* ob = xnT + b * (kN * kC) + g * 8;
#pragma unroll
  for (int kk = 0; kk < 4; ++kk) {
    const int t = tid + kk * 1024;
    u16x8 pk;
#pragma unroll
    for (int c = 0; c < 8; ++c) pk[c] = f2bf(vals[kk][c] * wv[c] + bv[c]);
    *reinterpret_cast<u16x8*>(ob + t * kC) = pk;
  }
}

// ---------------------------------------------------------------------------
// QKV GEMM. Epilogue: qT/kT[bh][t][64] pre-scaled (Q also folds log2e).
// r19: V stored with the SWAPPED-QK^T slot permutation: within each
// 32-column block, stored index m holds actual s where
//   m = 8*((s&15)>>2) + 4*(s>>4) + (s&3)
// i.e. with s_in = (nt&1)*16 + col:  m = 8*(col>>2) + 4*(nt&1) + (col&3).
// MFMA contracts slot-by-slot, so P/V agreement keeps the product exact.
// ---------------------------------------------------------------------------
__global__ __launch_bounds__(256) void qkv_gemm(const u16* __restrict__ qkvw,
                                                const float* __restrict__ qkvb,
                                                const u16* __restrict__ xnT,
                                                u16* __restrict__ qt,
                                                u16* __restrict__ kt,
                                                u16* __restrict__ vv) {
  const int nblk = blockIdx.x, mblk = blockIdx.y, b = blockIdx.z;
  const int tid = threadIdx.x;
  const int w = tid >> 6, l = tid & 63, quad = l >> 4, col = l & 15;
  const int m0 = mblk * 64 + w * 16;
  const int n0 = nblk * 64;
  const u16* xb = xnT + b * (kN * kC);
  f32x4 acc[4] = {{0,0,0,0},{0,0,0,0},{0,0,0,0},{0,0,0,0}};
  const u16* ap = qkvw + (m0 + col) * kC + quad * 8;
  const u16* bp = xb + (n0 + col) * kC + quad * 8;
#pragma unroll
  for (int ks = 0; ks < 8; ++ks) {
    const bf16x8 af = ldb8(ap + ks * 32);
#pragma unroll
    for (int nt = 0; nt < 4; ++nt) {
      const bf16x8 bfr = ldb8(bp + nt * (16 * kC) + ks * 32);
      acc[nt] = MFMA16x16x32(af, bfr, acc[nt]);
    }
  }
  const int o_base = m0 + quad * 4;
  const int head = o_base / 192;
  const int rr = o_base % 192;
  const int bh = b * kHeads + head;
  const int seg = rr >> 6;
  const int c0 = rr & 63;
  float bias[4];
#pragma unroll
  for (int r = 0; r < 4; ++r) bias[r] = qkvb[o_base + r];
  const float sc = (seg == 0) ? kScaleQ : kScale;
#pragma unroll
  for (int nt = 0; nt < 4; ++nt) {
    const int t = n0 + nt * 16 + col;
    if (seg == 2) {
      // r19 permuted position within the 32-block (see header comment)
      const int tp = n0 + (nt >> 1) * 32 + 8 * (col >> 2) + 4 * (nt & 1) + (col & 3);
#pragma unroll
      for (int r = 0; r < 4; ++r)
        vv[bh * (kD * kN) + (c0 + r) * kN + tp] = f2bf(acc[nt][r] + bias[r]);
    } else {
      u16* dst = (seg == 0 ? qt : kt) + bh * (kN * kD) + t * kD + c0;
      u16x4 pk;
#pragma unroll
      for (int r = 0; r < 4; ++r) pk[r] = f2bf((acc[nt][r] + bias[r]) * sc);
      *reinterpret_cast<u16x4*>(dst) = pk;
    }
  }
}

// ---------------------------------------------------------------------------
// Flash attention, swapped-QK^T register form + cooperative K/V LDS staging.
// r19 POST-MORTEM: removing the P LDS round-trip changed NOTHING (140.6us
// both ways). r18 showed 2x per-wave VMEM -> 1.8x dur. Diagnosis: the kernel
// is VMEM-request-rate bound; all 4 waves of a block loaded IDENTICAL K/V
// (8 gathers/wave/iter, 16 lines each = ~512 line-req/block-iter).
// r20: stage the 8KB K/V tile cooperatively ONCE per block per iter
// (256 thr x 32B, K src contiguous, V src 64B-dense) -> 2 VMEM instr/wave
// /iter (4x fewer requests). Double-buffered LDS, 1 barrier/iter, T14 split:
//   top of iter: ds_write staged regs (loaded during PREVIOUS iter) ->
//   barrier -> issue next-tile global loads -> compute current tile.
// Layouts (both sides use the same XOR involution, 16B granules):
//   K[32s][64d]: chunk c of row r stored at slot c^(r&7). Read k-frag:
//     [col(+16)][ (d0/8+quad) ^ (col&7) ].
//   V packed 2 d-rows per 128B row: row = d>>1, content (a=d&1, chunk q)
//     at slot (4a+q)^(row&7). Read vf[ct]: row = ct*8+(col>>1),
//     slot = (4*(col&1)+quad) ^ (col>>1).
// Uniform 8 accesses/bank on reads+writes (conflict-free b128).
// ---------------------------------------------------------------------------
__global__ __launch_bounds__(256, 2) void attn_split(const u16* __restrict__ qt,
                                                     const u16* __restrict__ kt,
                                                     const u16* __restrict__ vv,
                                                     float* __restrict__ pO,
                                                     float* __restrict__ pl) {
  const int tblk = blockIdx.x, bh = blockIdx.y, z = blockIdx.z;
  const int tid = threadIdx.x;
  const int w = tid >> 6, l = tid & 63, quad = l >> 4, col = l & 15;
  const int t0 = tblk * 256 + w * 64;
  const u16* qb = qt + bh * (kN * kD);
  const u16* kb = kt + bh * (kN * kD);
  const u16* vb = vv + bh * (kD * kN);
  bf16x8 qf[4][2];
#pragma unroll
  for (int ti = 0; ti < 4; ++ti) {
    qf[ti][0] = ldb8(qb + (t0 + ti * 16 + col) * kD + quad * 8);
    qf[ti][1] = ldb8(qb + (t0 + ti * 16 + col) * kD + 32 + quad * 8);
  }
  u16x8 ones_u;
#pragma unroll
  for (int i = 0; i < 8; ++i) ones_u[i] = 0x3f80;  // bf16 1.0
  const bf16x8 onesf = *reinterpret_cast<bf16x8*>(&ones_u);
  f32x4 oacc[4][4];
  f32x4 lacc[4];
#pragma unroll
  for (int ti = 0; ti < 4; ++ti) {
    lacc[ti] = f32x4{0, 0, 0, 0};
#pragma unroll
    for (int ct = 0; ct < 4; ++ct) oacc[ti][ct] = f32x4{0, 0, 0, 0};
  }

  __shared__ __align__(16) u16 kls[2][32][64];   // 8 KiB
  __shared__ __align__(16) u16 vls[2][32][64];   // 8 KiB
  constexpr int NIT = (kN / kSplit) / 32;        // 32
  const int s_beg = z * (kN / kSplit);

  // --- staging thread roles (uniform over the loop) ---
  const int srow = tid >> 3, sk8 = tid & 7, skey = srow & 7;
  // K: linear source chunk sk8 of row srow -> swizzled slot sk8^skey
  const u16* ksrc = kb + (size_t)(s_beg + srow) * kD + sk8 * 8;
  u16* kdst = &kls[0][srow][((sk8 ^ skey)) * 8];
  // V: source (d = 2*srow+a, chunk q) -> slot (4a+q)^skey
  const int sa = sk8 >> 2, sq = sk8 & 3;
  const u16* vsrc = vb + (size_t)(2 * srow + sa) * kN + s_beg + sq * 8;
  u16* vdst = &vls[0][srow][(((sa << 2) | sq) ^ skey) * 8];

  // prologue: load tile 0 into staging regs
  bf16x8 kstg = ldb8(ksrc);
  bf16x8 vstg = ldb8(vsrc);

  for (int it = 0; it < NIT; ++it) {
    const int cb = (it & 1) * (32 * 64);
    // write tile `it` (regs were loaded a full iteration ago)
    *reinterpret_cast<bf16x8*>(kdst + cb) = kstg;
    *reinterpret_cast<bf16x8*>(vdst + cb) = vstg;
    __syncthreads();
    // issue next-tile loads; latency hidden under this iter's compute
    if (it + 1 < NIT) {
      kstg = ldb8(ksrc + (size_t)(it + 1) * (32 * kD));
      vstg = ldb8(vsrc + (it + 1) * 32);
    }
    const u16* kl = &kls[0][0][0] + cb;
    const u16* vl = &vls[0][0][0] + cb;
    const int kx = (col & 7) * 8;
    const bf16x8 k00 = ldb8(kl + col * 64 + ((quad * 8) ^ kx));
    const bf16x8 k01 = ldb8(kl + col * 64 + ((32 + quad * 8) ^ kx));
    const bf16x8 k10 = ldb8(kl + (col + 16) * 64 + ((quad * 8) ^ kx));
    const bf16x8 k11 = ldb8(kl + (col + 16) * 64 + ((32 + quad * 8) ^ kx));
    bf16x8 vf[4];
    const int vslot = (((col & 1) << 2) | quad) ^ (col >> 1);
#pragma unroll
    for (int ct = 0; ct < 4; ++ct)
      vf[ct] = ldb8(vl + (ct * 8 + (col >> 1)) * 64 + vslot * 8);
#pragma unroll
    for (int ti = 0; ti < 4; ++ti) {
      // swapped: A = K (rows = s), B = Q (cols = q)
      f32x4 sa0 = {0, 0, 0, 0}, sa1 = {0, 0, 0, 0};
      sa0 = MFMA16x16x32(k00, qf[ti][0], sa0);
      sa0 = MFMA16x16x32(k01, qf[ti][1], sa0);
      sa1 = MFMA16x16x32(k10, qf[ti][0], sa1);
      sa1 = MFMA16x16x32(k11, qf[ti][1], sa1);
      // lane holds P[q=col][s]: sa0[r] -> s=s0+quad*4+r, sa1[r] -> +16.
      const u32 e00 = __float_as_uint(exp2f(sa0[0]));
      const u32 e01 = __float_as_uint(exp2f(sa0[1]));
      const u32 e02 = __float_as_uint(exp2f(sa0[2]));
      const u32 e03 = __float_as_uint(exp2f(sa0[3]));
      const u32 e10 = __float_as_uint(exp2f(sa1[0]));
      const u32 e11 = __float_as_uint(exp2f(sa1[1]));
      const u32 e12 = __float_as_uint(exp2f(sa1[2]));
      const u32 e13 = __float_as_uint(exp2f(sa1[3]));
      union { u32 wd[4]; bf16x8 v; } pa;
      // perm(a,b,0x07060302): lo16 = bf16_rtz(b), hi16 = bf16_rtz(a)
      pa.wd[0] = __builtin_amdgcn_perm(e01, e00, 0x07060302u);
      pa.wd[1] = __builtin_amdgcn_perm(e03, e02, 0x07060302u);
      pa.wd[2] = __builtin_amdgcn_perm(e11, e10, 0x07060302u);
      pa.wd[3] = __builtin_amdgcn_perm(e13, e12, 0x07060302u);
#pragma unroll
      for (int ct = 0; ct < 4; ++ct)
        oacc[ti][ct] = MFMA16x16x32(pa.v, vf[ct], oacc[ti][ct]);
      lacc[ti] = MFMA16x16x32(pa.v, onesf, lacc[ti]);
    }
  }
  float* po = pO + (size_t)(z * 16 + bh) * kN * kD;
  float* plp = pl + (size_t)(z * 16 + bh) * kN;
#pragma unroll
  for (int ti = 0; ti < 4; ++ti)
#pragma unroll
    for (int r = 0; r < 4; ++r) {
      const int t = t0 + ti * 16 + quad * 4 + r;
#pragma unroll
      for (int ct = 0; ct < 4; ++ct)
        po[(size_t)t * kD + ct * 16 + col] = oacc[ti][ct][r];
      if (col == 0) plp[t] = lacc[ti][r];
    }
}

// ---------------------------------------------------------------------------
// Combine 4 split partials: O = sum_z O_z / sum_z l_z -> ht[b][t][c] bf16.
// ---------------------------------------------------------------------------
__global__ __launch_bounds__(256) void attn_combine(const float* __restrict__ pO,
                                                    const float* __restrict__ pl,
                                                    u16* __restrict__ ht) {
  const int idx = blockIdx.x * 256 + threadIdx.x;   // 16bh * 4096t * 16chunks
  const int c0 = (idx & 15) * 4;
  const int t = (idx >> 4) & (kN - 1);
  const int bh = idx >> 16;
  f32x4 acc = {0, 0, 0, 0};
  float lsum = 0.f;
#pragma unroll
  for (int z = 0; z < kSplit; ++z) {
    const size_t base = ((size_t)(z * 16 + bh) * kN + t);
    acc += *reinterpret_cast<const f32x4*>(pO + base * kD + c0);
    lsum += pl[base];
  }
  const float inv = 1.f / lsum;
  u16x4 pk;
#pragma unroll
  for (int i = 0; i < 4; ++i) pk[i] = f2bf(acc[i] * inv);
  const int b = bh >> 2, head = bh & 3;
  *reinterpret_cast<u16x4*>(ht + (size_t)b * (kN * kC) + (size_t)t * kC +
                            head * kD + c0) = pk;
}

// ---------------------------------------------------------------------------
// Proj GEMM + bias + residual: out fp32 (B,C,H,W). Validated r6.
// ---------------------------------------------------------------------------
__global__ __launch_bounds__(256) void proj_kernel(const u16* __restrict__ projw,
                                                   const float* __restrict__ projb,
                                                   const u16* __restrict__ ht,
                                                   const float* __restrict__ x,
                                                   float* __restrict__ out) {
  const int nblk = blockIdx.x, mblk = blockIdx.y, b = blockIdx.z;
  const int tid = threadIdx.x;
  const int w = tid >> 6, l = tid & 63, quad = l >> 4, col = l & 15;
  const int m0 = mblk * 64 + w * 16;
  const int n0 = nblk * 64;
  const u16* hb = ht + b * (kN * kC);
  f32x4 acc[4] = {{0,0,0,0},{0,0,0,0},{0,0,0,0},{0,0,0,0}};
  const u16* ap = projw + (m0 + col) * kC + quad * 8;
  const u16* bp = hb + (n0 + col) * kC + quad * 8;
#pragma unroll
  for (int ks = 0; ks < 8; ++ks) {
    const bf16x8 af = ldb8(ap + ks * 32);
#pragma unroll
    for (int nt = 0; nt < 4; ++nt) {
      const bf16x8 bfr = ldb8(bp + nt * (16 * kC) + ks * 32);
      acc[nt] = MFMA16x16x32(af, bfr, acc[nt]);
    }
  }
#pragma unroll
  for (int nt = 0; nt < 4; ++nt) {
    const int t = n0 + nt * 16 + col;
#pragma unroll
    for (int r = 0; r < 4; ++r) {
      const int o = m0 + quad * 4 + r;
      const int idx = b * (kC * kN) + o * kN + t;
      out[idx] = acc[nt][r] + projb[o] + x[idx];
    }
  }
}

extern "C" void kernel_launch(void* const* d_in, const int* in_sizes, int n_in,
                              void* d_out, int out_size, void* d_ws, size_t ws_size,
                              hipStream_t stream) {
  const float* x = (const float*)d_in[0];
  const float* gnw = (const float*)d_in[1];
  const float* gnb = (const float*)d_in[2];
  const float* qkvw_f = (const float*)d_in[3];
  const float* qkvb = (const float*)d_in[4];
  const float* projw_f = (const float*)d_in[5];
  const float* projb = (const float*)d_in[6];
  float* out = (float*)d_out;

  char* ws = (char*)d_ws;
  u16* xnT = (u16*)(ws);                      // 8 MiB
  u16* qt = (u16*)(ws + (8u << 20));          // 8 MiB
  u16* kt = (u16*)(ws + (16u << 20));         // 8 MiB
  u16* vv = (u16*)(ws + (24u << 20));         // 8 MiB
  u16* ht = (u16*)(ws + (32u << 20));         // 8 MiB
  u16* qkvw = (u16*)(ws + (40u << 20));       // 384 KiB
  u16* projw = (u16*)(ws + (41u << 20));      // 128 KiB
  float* pO = (float*)(ws + (48u << 20));     // 64 MiB (4 splits)
  float* pl = (float*)(ws + (112u << 20));    // 1 MiB

  convert_bf16<<<dim3(192), dim3(256), 0, stream>>>(qkvw_f, qkvw, 768 * kC);
  convert_bf16<<<dim3(64), dim3(256), 0, stream>>>(projw_f, projw, kC * kC);
  gn_kernel<<<dim3(32, 4), dim3(1024), 0, stream>>>(x, gnw, gnb, xnT);
  qkv_gemm<<<dim3(64, 12, 4), dim3(256), 0, stream>>>(qkvw, qkvb, xnT, qt, kt, vv);
  attn_split<<<dim3(16, 16, kSplit), dim3(256), 0, stream>>>(qt, kt, vv, pO, pl);
  attn_combine<<<dim3(4096), dim3(256), 0, stream>>>(pO, pl, ht);
  proj_kernel<<<dim3(64, 4, 4), dim3(256), 0, stream>>>(projw, projb, ht, x, out);
}

// Round 7
// 251.282 us; speedup vs baseline: 1.6527x; 1.1151x over previous
//
#include <hip/hip_runtime.h>

typedef unsigned short u16;
typedef unsigned int u32;
typedef __bf16 bf16x8 __attribute__((ext_vector_type(8)));
typedef float f32x4 __attribute__((ext_vector_type(4)));
typedef u16 u16x4 __attribute__((ext_vector_type(4)));
typedef u16 u16x8 __attribute__((ext_vector_type(8)));

#define MFMA16x16x32(a, b, c) __builtin_amdgcn_mfma_f32_16x16x32_bf16((a), (b), (c), 0, 0, 0)

static constexpr int kB = 4;
static constexpr int kC = 256;
static constexpr int kN = 4096;     // H*W
static constexpr int kHeads = 4;    // per batch
static constexpr int kD = 64;       // head dim
static constexpr int kSplit = 4;
static constexpr float kScale = 0.35355339059327373f;   // 64^-0.25 (K side)
static constexpr float kScaleQ = 0.51006971545f;        // 64^-0.25 * log2(e) (Q side)

__device__ __forceinline__ u16 f2bf(float f) {
  union { float f; u32 i; } v; v.f = f;
  return (u16)((v.i + 0x7fffu + ((v.i >> 16) & 1u)) >> 16);
}
__device__ __forceinline__ bf16x8 ldb8(const u16* p) {
  return *reinterpret_cast<const bf16x8*>(p);
}
// r21: raw v_exp_f32 (2^x). exp2f() is the OCML entry with range/denormal
// fixup VALU around the hardware op; we only need the hw op (bf16 epilogue
// flushes denormals anyway).
__device__ __forceinline__ float fast_exp2(float x) {
#if __has_builtin(__builtin_amdgcn_exp2f)
  return __builtin_amdgcn_exp2f(x);
#else
  float r;
  asm("v_exp_f32 %0, %1" : "=v"(r) : "v"(x));
  return r;
#endif
}

// ---------------------------------------------------------------------------
// fp32 -> bf16 weight conversion (grid-stride).
// ---------------------------------------------------------------------------
__global__ void convert_bf16(const float* __restrict__ in, u16* __restrict__ out,
                             int n) {
  for (int i = blockIdx.x * blockDim.x + threadIdx.x; i < n;
       i += gridDim.x * blockDim.x)
    out[i] = f2bf(in[i]);
}

// ---------------------------------------------------------------------------
// GroupNorm (validated r4). Writes bf16 transposed xnT[b][t][c].
// ---------------------------------------------------------------------------
__global__ __launch_bounds__(1024) void gn_kernel(const float* __restrict__ x,
                                                  const float* __restrict__ gnw,
                                                  const float* __restrict__ gnb,
                                                  u16* __restrict__ xnT) {
  const int g = blockIdx.x, b = blockIdx.y;
  const int tid = threadIdx.x;
  const float* xb = x + b * (kC * kN) + g * 8 * kN;
  float vals[4][8];
  float s = 0.f, ss = 0.f;
#pragma unroll
  for (int kk = 0; kk < 4; ++kk) {
    const int t = tid + kk * 1024;
#pragma unroll
    for (int c = 0; c < 8; ++c) {
      const float v_ = xb[c * kN + t];
      vals[kk][c] = v_;
      s += v_; ss += v_ * v_;
    }
  }
#pragma unroll
  for (int off = 32; off > 0; off >>= 1) {
    s += __shfl_down(s, off);
    ss += __shfl_down(ss, off);
  }
  __shared__ float rbuf[32];
  const int wid = tid >> 6, lane = tid & 63;
  if (lane == 0) { rbuf[wid] = s; rbuf[16 + wid] = ss; }
  __syncthreads();
  if (tid < 64) {
    float s2 = (lane < 16) ? rbuf[lane] : 0.f;
    float ss2 = (lane < 16) ? rbuf[16 + lane] : 0.f;
#pragma unroll
    for (int off = 8; off > 0; off >>= 1) {
      s2 += __shfl_down(s2, off);
      ss2 += __shfl_down(ss2, off);
    }
    if (lane == 0) { rbuf[0] = s2; rbuf[1] = ss2; }
  }
  __syncthreads();
  const float inv_n = 1.f / 32768.f;
  const float mu = rbuf[0] * inv_n;
  const float var = rbuf[1] * inv_n - mu * mu;
  const float rs = rsqrtf(var + 1e-5f);
  float wv[8], bv[8];
#pragma unroll
  for (int c = 0; c < 8; ++c) {
    const float wgt = gnw[g * 8 + c] * rs;
    wv[c] = wgt;
    bv[c] = gnb[g * 8 + c] - mu * wgt;
  }
  u16* ob = xnT + b * (kN * kC) + g * 8;
#pragma unroll
  for (int kk = 0; kk < 4; ++kk) {
    const int t = tid + kk * 1024;
    u16x8 pk;
#pragma unroll
    for (int c = 0; c < 8; ++c) pk[c] = f2bf(vals[kk][c] * wv[c] + bv[c]);
    *reinterpret_cast<u16x8*>(ob + t * kC) = pk;
  }
}

// ---------------------------------------------------------------------------
// QKV GEMM. Epilogue: qT/kT[bh][t][64] pre-scaled (Q also folds log2e).
// r19: V stored with the SWAPPED-QK^T slot permutation: within each
// 32-column block, stored index m holds actual s where
//   m = 8*((s&15)>>2) + 4*(s>>4) + (s&3)
// i.e. with s_in = (nt&1)*16 + col:  m = 8*(col>>2) + 4*(nt&1) + (col&3).
// MFMA contracts slot-by-slot, so P/V agreement keeps the product exact.
// ---------------------------------------------------------------------------
__global__ __launch_bounds__(256) void qkv_gemm(const u16* __restrict__ qkvw,
                                                const float* __restrict__ qkvb,
                                                const u16* __restrict__ xnT,
                                                u16* __restrict__ qt,
                                                u16* __restrict__ kt,
                                                u16* __restrict__ vv) {
  const int nblk = blockIdx.x, mblk = blockIdx.y, b = blockIdx.z;
  const int tid = threadIdx.x;
  const int w = tid >> 6, l = tid & 63, quad = l >> 4, col = l & 15;
  const int m0 = mblk * 64 + w * 16;
  const int n0 = nblk * 64;
  const u16* xb = xnT + b * (kN * kC);
  f32x4 acc[4] = {{0,0,0,0},{0,0,0,0},{0,0,0,0},{0,0,0,0}};
  const u16* ap = qkvw + (m0 + col) * kC + quad * 8;
  const u16* bp = xb + (n0 + col) * kC + quad * 8;
#pragma unroll
  for (int ks = 0; ks < 8; ++ks) {
    const bf16x8 af = ldb8(ap + ks * 32);
#pragma unroll
    for (int nt = 0; nt < 4; ++nt) {
      const bf16x8 bfr = ldb8(bp + nt * (16 * kC) + ks * 32);
      acc[nt] = MFMA16x16x32(af, bfr, acc[nt]);
    }
  }
  const int o_base = m0 + quad * 4;
  const int head = o_base / 192;
  const int rr = o_base % 192;
  const int bh = b * kHeads + head;
  const int seg = rr >> 6;
  const int c0 = rr & 63;
  float bias[4];
#pragma unroll
  for (int r = 0; r < 4; ++r) bias[r] = qkvb[o_base + r];
  const float sc = (seg == 0) ? kScaleQ : kScale;
#pragma unroll
  for (int nt = 0; nt < 4; ++nt) {
    const int t = n0 + nt * 16 + col;
    if (seg == 2) {
      // r19 permuted position within the 32-block (see header comment)
      const int tp = n0 + (nt >> 1) * 32 + 8 * (col >> 2) + 4 * (nt & 1) + (col & 3);
#pragma unroll
      for (int r = 0; r < 4; ++r)
        vv[bh * (kD * kN) + (c0 + r) * kN + tp] = f2bf(acc[nt][r] + bias[r]);
    } else {
      u16* dst = (seg == 0 ? qt : kt) + bh * (kN * kD) + t * kD + c0;
      u16x4 pk;
#pragma unroll
      for (int r = 0; r < 4; ++r) pk[r] = f2bf((acc[nt][r] + bias[r]) * sc);
      *reinterpret_cast<u16x4*>(dst) = pk;
    }
  }
}

// ---------------------------------------------------------------------------
// Flash attention, swapped-QK^T register form + cooperative K/V LDS staging.
// r20 (validated, 140.6->111us): stage the 8KB K/V tile cooperatively ONCE
// per block per iter (256 thr x 32B) -> 2 VMEM instr/wave/iter. Double-
// buffered LDS, 1 barrier/iter, T14 split. XOR-involution swizzles on both
// write and read sides; SQ_LDS_BANK_CONFLICT == 0 measured.
// r21: VALUBusy was 57% (63us absolute, > MFMA's 32us). exp2f() is the OCML
// wrapper with range-fixup VALU around v_exp_f32; replace with the raw
// builtin (fast_exp2). Also unroll the it-loop by 2 so the double-buffer
// offset cb is a compile-time constant per copy (LDS addrs loop-invariant).
// ---------------------------------------------------------------------------
__global__ __launch_bounds__(256, 2) void attn_split(const u16* __restrict__ qt,
                                                     const u16* __restrict__ kt,
                                                     const u16* __restrict__ vv,
                                                     float* __restrict__ pO,
                                                     float* __restrict__ pl) {
  const int tblk = blockIdx.x, bh = blockIdx.y, z = blockIdx.z;
  const int tid = threadIdx.x;
  const int w = tid >> 6, l = tid & 63, quad = l >> 4, col = l & 15;
  const int t0 = tblk * 256 + w * 64;
  const u16* qb = qt + bh * (kN * kD);
  const u16* kb = kt + bh * (kN * kD);
  const u16* vb = vv + bh * (kD * kN);
  bf16x8 qf[4][2];
#pragma unroll
  for (int ti = 0; ti < 4; ++ti) {
    qf[ti][0] = ldb8(qb + (t0 + ti * 16 + col) * kD + quad * 8);
    qf[ti][1] = ldb8(qb + (t0 + ti * 16 + col) * kD + 32 + quad * 8);
  }
  u16x8 ones_u;
#pragma unroll
  for (int i = 0; i < 8; ++i) ones_u[i] = 0x3f80;  // bf16 1.0
  const bf16x8 onesf = *reinterpret_cast<bf16x8*>(&ones_u);
  f32x4 oacc[4][4];
  f32x4 lacc[4];
#pragma unroll
  for (int ti = 0; ti < 4; ++ti) {
    lacc[ti] = f32x4{0, 0, 0, 0};
#pragma unroll
    for (int ct = 0; ct < 4; ++ct) oacc[ti][ct] = f32x4{0, 0, 0, 0};
  }

  __shared__ __align__(16) u16 kls[2][32][64];   // 8 KiB
  __shared__ __align__(16) u16 vls[2][32][64];   // 8 KiB
  constexpr int NIT = (kN / kSplit) / 32;        // 32
  const int s_beg = z * (kN / kSplit);

  // --- staging thread roles (uniform over the loop) ---
  const int srow = tid >> 3, sk8 = tid & 7, skey = srow & 7;
  // K: linear source chunk sk8 of row srow -> swizzled slot sk8^skey
  const u16* ksrc = kb + (size_t)(s_beg + srow) * kD + sk8 * 8;
  u16* kdst = &kls[0][srow][((sk8 ^ skey)) * 8];
  // V: source (d = 2*srow+a, chunk q) -> slot (4a+q)^skey
  const int sa = sk8 >> 2, sq = sk8 & 3;
  const u16* vsrc = vb + (size_t)(2 * srow + sa) * kN + s_beg + sq * 8;
  u16* vdst = &vls[0][srow][(((sa << 2) | sq) ^ skey) * 8];

  // prologue: load tile 0 into staging regs
  bf16x8 kstg = ldb8(ksrc);
  bf16x8 vstg = ldb8(vsrc);

#pragma unroll 2
  for (int it = 0; it < NIT; ++it) {
    const int cb = (it & 1) * (32 * 64);
    // write tile `it` (regs were loaded a full iteration ago)
    *reinterpret_cast<bf16x8*>(kdst + cb) = kstg;
    *reinterpret_cast<bf16x8*>(vdst + cb) = vstg;
    __syncthreads();
    // issue next-tile loads; latency hidden under this iter's compute
    if (it + 1 < NIT) {
      kstg = ldb8(ksrc + (size_t)(it + 1) * (32 * kD));
      vstg = ldb8(vsrc + (it + 1) * 32);
    }
    const u16* kl = &kls[0][0][0] + cb;
    const u16* vl = &vls[0][0][0] + cb;
    const int kx = (col & 7) * 8;
    const bf16x8 k00 = ldb8(kl + col * 64 + ((quad * 8) ^ kx));
    const bf16x8 k01 = ldb8(kl + col * 64 + ((32 + quad * 8) ^ kx));
    const bf16x8 k10 = ldb8(kl + (col + 16) * 64 + ((quad * 8) ^ kx));
    const bf16x8 k11 = ldb8(kl + (col + 16) * 64 + ((32 + quad * 8) ^ kx));
    bf16x8 vf[4];
    const int vslot = (((col & 1) << 2) | quad) ^ (col >> 1);
#pragma unroll
    for (int ct = 0; ct < 4; ++ct)
      vf[ct] = ldb8(vl + (ct * 8 + (col >> 1)) * 64 + vslot * 8);
#pragma unroll
    for (int ti = 0; ti < 4; ++ti) {
      // swapped: A = K (rows = s), B = Q (cols = q)
      f32x4 sa0 = {0, 0, 0, 0}, sa1 = {0, 0, 0, 0};
      sa0 = MFMA16x16x32(k00, qf[ti][0], sa0);
      sa0 = MFMA16x16x32(k01, qf[ti][1], sa0);
      sa1 = MFMA16x16x32(k10, qf[ti][0], sa1);
      sa1 = MFMA16x16x32(k11, qf[ti][1], sa1);
      // lane holds P[q=col][s]: sa0[r] -> s=s0+quad*4+r, sa1[r] -> +16.
      const u32 e00 = __float_as_uint(fast_exp2(sa0[0]));
      const u32 e01 = __float_as_uint(fast_exp2(sa0[1]));
      const u32 e02 = __float_as_uint(fast_exp2(sa0[2]));
      const u32 e03 = __float_as_uint(fast_exp2(sa0[3]));
      const u32 e10 = __float_as_uint(fast_exp2(sa1[0]));
      const u32 e11 = __float_as_uint(fast_exp2(sa1[1]));
      const u32 e12 = __float_as_uint(fast_exp2(sa1[2]));
      const u32 e13 = __float_as_uint(fast_exp2(sa1[3]));
      union { u32 wd[4]; bf16x8 v; } pa;
      // perm(a,b,0x07060302): lo16 = bf16_rtz(b), hi16 = bf16_rtz(a)
      pa.wd[0] = __builtin_amdgcn_perm(e01, e00, 0x07060302u);
      pa.wd[1] = __builtin_amdgcn_perm(e03, e02, 0x07060302u);
      pa.wd[2] = __builtin_amdgcn_perm(e11, e10, 0x07060302u);
      pa.wd[3] = __builtin_amdgcn_perm(e13, e12, 0x07060302u);
#pragma unroll
      for (int ct = 0; ct < 4; ++ct)
        oacc[ti][ct] = MFMA16x16x32(pa.v, vf[ct], oacc[ti][ct]);
      lacc[ti] = MFMA16x16x32(pa.v, onesf, lacc[ti]);
    }
  }
  float* po = pO + (size_t)(z * 16 + bh) * kN * kD;
  float* plp = pl + (size_t)(z * 16 + bh) * kN;
#pragma unroll
  for (int ti = 0; ti < 4; ++ti)
#pragma unroll
    for (int r = 0; r < 4; ++r) {
      const int t = t0 + ti * 16 + quad * 4 + r;
#pragma unroll
      for (int ct = 0; ct < 4; ++ct)
        po[(size_t)t * kD + ct * 16 + col] = oacc[ti][ct][r];
      if (col == 0) plp[t] = lacc[ti][r];
    }
}

// ---------------------------------------------------------------------------
// Combine 4 split partials: O = sum_z O_z / sum_z l_z -> ht[b][t][c] bf16.
// ---------------------------------------------------------------------------
__global__ __launch_bounds__(256) void attn_combine(const float* __restrict__ pO,
                                                    const float* __restrict__ pl,
                                                    u16* __restrict__ ht) {
  const int idx = blockIdx.x * 256 + threadIdx.x;   // 16bh * 4096t * 16chunks
  const int c0 = (idx & 15) * 4;
  const int t = (idx >> 4) & (kN - 1);
  const int bh = idx >> 16;
  f32x4 acc = {0, 0, 0, 0};
  float lsum = 0.f;
#pragma unroll
  for (int z = 0; z < kSplit; ++z) {
    const size_t base = ((size_t)(z * 16 + bh) * kN + t);
    acc += *reinterpret_cast<const f32x4*>(pO + base * kD + c0);
    lsum += pl[base];
  }
  const float inv = 1.f / lsum;
  u16x4 pk;
#pragma unroll
  for (int i = 0; i < 4; ++i) pk[i] = f2bf(acc[i] * inv);
  const int b = bh >> 2, head = bh & 3;
  *reinterpret_cast<u16x4*>(ht + (size_t)b * (kN * kC) + (size_t)t * kC +
                            head * kD + c0) = pk;
}

// ---------------------------------------------------------------------------
// Proj GEMM + bias + residual: out fp32 (B,C,H,W). Validated r6.
// ---------------------------------------------------------------------------
__global__ __launch_bounds__(256) void proj_kernel(const u16* __restrict__ projw,
                                                   const float* __restrict__ projb,
                                                   const u16* __restrict__ ht,
                                                   const float* __restrict__ x,
                                                   float* __restrict__ out) {
  const int nblk = blockIdx.x, mblk = blockIdx.y, b = blockIdx.z;
  const int tid = threadIdx.x;
  const int w = tid >> 6, l = tid & 63, quad = l >> 4, col = l & 15;
  const int m0 = mblk * 64 + w * 16;
  const int n0 = nblk * 64;
  const u16* hb = ht + b * (kN * kC);
  f32x4 acc[4] = {{0,0,0,0},{0,0,0,0},{0,0,0,0},{0,0,0,0}};
  const u16* ap = projw + (m0 + col) * kC + quad * 8;
  const u16* bp = hb + (n0 + col) * kC + quad * 8;
#pragma unroll
  for (int ks = 0; ks < 8; ++ks) {
    const bf16x8 af = ldb8(ap + ks * 32);
#pragma unroll
    for (int nt = 0; nt < 4; ++nt) {
      const bf16x8 bfr = ldb8(bp + nt * (16 * kC) + ks * 32);
      acc[nt] = MFMA16x16x32(af, bfr, acc[nt]);
    }
  }
#pragma unroll
  for (int nt = 0; nt < 4; ++nt) {
    const int t = n0 + nt * 16 + col;
#pragma unroll
    for (int r = 0; r < 4; ++r) {
      const int o = m0 + quad * 4 + r;
      const int idx = b * (kC * kN) + o * kN + t;
      out[idx] = acc[nt][r] + projb[o] + x[idx];
    }
  }
}

extern "C" void kernel_launch(void* const* d_in, const int* in_sizes, int n_in,
                              void* d_out, int out_size, void* d_ws, size_t ws_size,
                              hipStream_t stream) {
  const float* x = (const float*)d_in[0];
  const float* gnw = (const float*)d_in[1];
  const float* gnb = (const float*)d_in[2];
  const float* qkvw_f = (const float*)d_in[3];
  const float* qkvb = (const float*)d_in[4];
  const float* projw_f = (const float*)d_in[5];
  const float* projb = (const float*)d_in[6];
  float* out = (float*)d_out;

  char* ws = (char*)d_ws;
  u16* xnT = (u16*)(ws);                      // 8 MiB
  u16* qt = (u16*)(ws + (8u << 20));          // 8 MiB
  u16* kt = (u16*)(ws + (16u << 20));         // 8 MiB
  u16* vv = (u16*)(ws + (24u << 20));         // 8 MiB
  u16* ht = (u16*)(ws + (32u << 20));         // 8 MiB
  u16* qkvw = (u16*)(ws + (40u << 20));       // 384 KiB
  u16* projw = (u16*)(ws + (41u << 20));      // 128 KiB
  float* pO = (float*)(ws + (48u << 20));     // 64 MiB (4 splits)
  float* pl = (float*)(ws + (112u << 20));    // 1 MiB

  convert_bf16<<<dim3(192), dim3(256), 0, stream>>>(qkvw_f, qkvw, 768 * kC);
  convert_bf16<<<dim3(64), dim3(256), 0, stream>>>(projw_f, projw, kC * kC);
  gn_kernel<<<dim3(32, 4), dim3(1024), 0, stream>>>(x, gnw, gnb, xnT);
  qkv_gemm<<<dim3(64, 12, 4), dim3(256), 0, stream>>>(qkvw, qkvb, xnT, qt, kt, vv);
  attn_split<<<dim3(16, 16, kSplit), dim3(256), 0, stream>>>(qt, kt, vv, pO, pl);
  attn_combine<<<dim3(4096), dim3(256), 0, stream>>>(pO, pl, ht);
  proj_kernel<<<dim3(64, 4, 4), dim3(256), 0, stream>>>(projw, projb, ht, x, out);
}

// Round 9
// 204.111 us; speedup vs baseline: 2.0346x; 1.2311x over previous
//
#include <hip/hip_runtime.h>

typedef unsigned short u16;
typedef unsigned int u32;
typedef __bf16 bf16x8 __attribute__((ext_vector_type(8)));
typedef float f32x4 __attribute__((ext_vector_type(4)));
typedef u16 u16x4 __attribute__((ext_vector_type(4)));
typedef u16 u16x8 __attribute__((ext_vector_type(8)));

#define MFMA16x16x32(a, b, c) __builtin_amdgcn_mfma_f32_16x16x32_bf16((a), (b), (c), 0, 0, 0)

static constexpr int kB = 4;
static constexpr int kC = 256;
static constexpr int kN = 4096;     // H*W
static constexpr int kHeads = 4;    // per batch
static constexpr int kD = 64;       // head dim
static constexpr int kSplit = 4;
static constexpr float kScale = 0.35355339059327373f;   // 64^-0.25 (K side)
static constexpr float kScaleQ = 0.51006971545f;        // 64^-0.25 * log2(e) (Q side)

__device__ __forceinline__ u16 f2bf(float f) {
  union { float f; u32 i; } v; v.f = f;
  return (u16)((v.i + 0x7fffu + ((v.i >> 16) & 1u)) >> 16);
}
__device__ __forceinline__ bf16x8 ldb8(const u16* p) {
  return *reinterpret_cast<const bf16x8*>(p);
}
// r21 (validated): raw v_exp_f32 (2^x); OCML exp2f carries fixup VALU.
__device__ __forceinline__ float fast_exp2(float x) {
#if __has_builtin(__builtin_amdgcn_exp2f)
  return __builtin_amdgcn_exp2f(x);
#else
  float r;
  asm("v_exp_f32 %0, %1" : "=v"(r) : "v"(x));
  return r;
#endif
}

// ---------------------------------------------------------------------------
// fp32 -> bf16 weight conversion (grid-stride).
// ---------------------------------------------------------------------------
__global__ void convert_bf16(const float* __restrict__ in, u16* __restrict__ out,
                             int n) {
  for (int i = blockIdx.x * blockDim.x + threadIdx.x; i < n;
       i += gridDim.x * blockDim.x)
    out[i] = f2bf(in[i]);
}

// ---------------------------------------------------------------------------
// GroupNorm (validated r4). Writes bf16 transposed xnT[b][t][c].
// ---------------------------------------------------------------------------
__global__ __launch_bounds__(1024) void gn_kernel(const float* __restrict__ x,
                                                  const float* __restrict__ gnw,
                                                  const float* __restrict__ gnb,
                                                  u16* __restrict__ xnT) {
  const int g = blockIdx.x, b = blockIdx.y;
  const int tid = threadIdx.x;
  const float* xb = x + b * (kC * kN) + g * 8 * kN;
  float vals[4][8];
  float s = 0.f, ss = 0.f;
#pragma unroll
  for (int kk = 0; kk < 4; ++kk) {
    const int t = tid + kk * 1024;
#pragma unroll
    for (int c = 0; c < 8; ++c) {
      const float v_ = xb[c * kN + t];
      vals[kk][c] = v_;
      s += v_; ss += v_ * v_;
    }
  }
#pragma unroll
  for (int off = 32; off > 0; off >>= 1) {
    s += __shfl_down(s, off);
    ss += __shfl_down(ss, off);
  }
  __shared__ float rbuf[32];
  const int wid = tid >> 6, lane = tid & 63;
  if (lane == 0) { rbuf[wid] = s; rbuf[16 + wid] = ss; }
  __syncthreads();
  if (tid < 64) {
    float s2 = (lane < 16) ? rbuf[lane] : 0.f;
    float ss2 = (lane < 16) ? rbuf[16 + lane] : 0.f;
#pragma unroll
    for (int off = 8; off > 0; off >>= 1) {
      s2 += __shfl_down(s2, off);
      ss2 += __shfl_down(ss2, off);
    }
    if (lane == 0) { rbuf[0] = s2; rbuf[1] = ss2; }
  }
  __syncthreads();
  const float inv_n = 1.f / 32768.f;
  const float mu = rbuf[0] * inv_n;
  const float var = rbuf[1] * inv_n - mu * mu;
  const float rs = rsqrtf(var + 1e-5f);
  float wv[8], bv[8];
#pragma unroll
  for (int c = 0; c < 8; ++c) {
    const float wgt = gnw[g * 8 + c] * rs;
    wv[c] = wgt;
    bv[c] = gnb[g * 8 + c] - mu * wgt;
  }
  u16* ob = xnT + b * (kN * kC) + g * 8;
#pragma unroll
  for (int kk = 0; kk < 4; ++kk) {
    const int t = tid + kk * 1024;
    u16x8 pk;
#pragma unroll
    for (int c = 0; c < 8; ++c) pk[c] = f2bf(vals[kk][c] * wv[c] + bv[c]);
    *reinterpret_cast<u16x8*>(ob + t * kC) = pk;
  }
}

// ---------------------------------------------------------------------------
// QKV GEMM. r22: r20's staging technique applied. A(64x256) and B(64x256)
// panels staged to LDS with fully COALESCED global loads (was: 16-line
// gathers per fragment load, B redundantly gathered by all 4 waves).
// Swizzle: 16B chunk c of row r stored at slot c^(r&7); fragment read at
// chunk (ks*4+quad)^(col&7) -> 2 lanes/bank aggregate (free).
// Epilogue unchanged (r19 V slot-permutation: within each 32-col block,
// stored index m = 8*(col>>2)+4*(nt&1)+(col&3) matches attn's in-register
// P fragment order; Q side folds log2e).
// ---------------------------------------------------------------------------
__global__ __launch_bounds__(256) void qkv_gemm(const u16* __restrict__ qkvw,
                                                const float* __restrict__ qkvb,
                                                const u16* __restrict__ xnT,
                                                u16* __restrict__ qt,
                                                u16* __restrict__ kt,
                                                u16* __restrict__ vv) {
  const int nblk = blockIdx.x, mblk = blockIdx.y, b = blockIdx.z;
  const int tid = threadIdx.x;
  const int w = tid >> 6, l = tid & 63, quad = l >> 4, col = l & 15;
  const int m0 = mblk * 64 + w * 16;
  const int n0 = nblk * 64;
  __shared__ __align__(16) u16 als[64 * 256];   // 32 KiB
  __shared__ __align__(16) u16 bls[64 * 256];   // 32 KiB
  {
    const u16* asrc = qkvw + (size_t)(mblk * 64) * kC;
    const u16* bsrc = xnT + (size_t)b * (kN * kC) + (size_t)n0 * kC;
#pragma unroll
    for (int p = 0; p < 8; ++p) {
      const int li = p * 256 + tid;        // [0,2048)
      const int row = li >> 5, ch = li & 31;
      const int sw = (ch ^ (row & 7)) * 8;
      *reinterpret_cast<bf16x8*>(&als[row * 256 + sw]) = ldb8(asrc + li * 8);
      *reinterpret_cast<bf16x8*>(&bls[row * 256 + sw]) = ldb8(bsrc + li * 8);
    }
  }
  __syncthreads();
  f32x4 acc[4] = {{0,0,0,0},{0,0,0,0},{0,0,0,0},{0,0,0,0}};
  const u16* arow = &als[(w * 16 + col) * 256];
  const int kx = col & 7;
#pragma unroll
  for (int ks = 0; ks < 8; ++ks) {
    const bf16x8 af = ldb8(arow + (((ks * 4 + quad) ^ kx)) * 8);
#pragma unroll
    for (int nt = 0; nt < 4; ++nt) {
      const bf16x8 bfr =
          ldb8(&bls[(nt * 16 + col) * 256 + (((ks * 4 + quad) ^ kx)) * 8]);
      acc[nt] = MFMA16x16x32(af, bfr, acc[nt]);
    }
  }
  const int o_base = m0 + quad * 4;
  const int head = o_base / 192;
  const int rr = o_base % 192;
  const int bh = b * kHeads + head;
  const int seg = rr >> 6;
  const int c0 = rr & 63;
  float bias[4];
#pragma unroll
  for (int r = 0; r < 4; ++r) bias[r] = qkvb[o_base + r];
  const float sc = (seg == 0) ? kScaleQ : kScale;
#pragma unroll
  for (int nt = 0; nt < 4; ++nt) {
    const int t = n0 + nt * 16 + col;
    if (seg == 2) {
      const int tp = n0 + (nt >> 1) * 32 + 8 * (col >> 2) + 4 * (nt & 1) + (col & 3);
#pragma unroll
      for (int r = 0; r < 4; ++r)
        vv[bh * (kD * kN) + (c0 + r) * kN + tp] = f2bf(acc[nt][r] + bias[r]);
    } else {
      u16* dst = (seg == 0 ? qt : kt) + bh * (kN * kD) + t * kD + c0;
      u16x4 pk;
#pragma unroll
      for (int r = 0; r < 4; ++r) pk[r] = f2bf((acc[nt][r] + bias[r]) * sc);
      *reinterpret_cast<u16x4*>(dst) = pk;
    }
  }
}

// ---------------------------------------------------------------------------
// Flash attention, swapped-QK^T register form + cooperative K/V LDS staging.
// r20 (validated): cooperative 8KB K/V staging, XOR-swizzled, dbuf, 1
// barrier/iter -> 140.6->111us. r21 (validated): fast_exp2 + unroll-2 ->
// 111->82.3us (VALU 63->28us). MfmaUtil 39%, bank conflicts 0.
// ---------------------------------------------------------------------------
__global__ __launch_bounds__(256, 2) void attn_split(const u16* __restrict__ qt,
                                                     const u16* __restrict__ kt,
                                                     const u16* __restrict__ vv,
                                                     float* __restrict__ pO,
                                                     float* __restrict__ pl) {
  const int tblk = blockIdx.x, bh = blockIdx.y, z = blockIdx.z;
  const int tid = threadIdx.x;
  const int w = tid >> 6, l = tid & 63, quad = l >> 4, col = l & 15;
  const int t0 = tblk * 256 + w * 64;
  const u16* qb = qt + bh * (kN * kD);
  const u16* kb = kt + bh * (kN * kD);
  const u16* vb = vv + bh * (kD * kN);
  bf16x8 qf[4][2];
#pragma unroll
  for (int ti = 0; ti < 4; ++ti) {
    qf[ti][0] = ldb8(qb + (t0 + ti * 16 + col) * kD + quad * 8);
    qf[ti][1] = ldb8(qb + (t0 + ti * 16 + col) * kD + 32 + quad * 8);
  }
  u16x8 ones_u;
#pragma unroll
  for (int i = 0; i < 8; ++i) ones_u[i] = 0x3f80;  // bf16 1.0
  const bf16x8 onesf = *reinterpret_cast<bf16x8*>(&ones_u);
  f32x4 oacc[4][4];
  f32x4 lacc[4];
#pragma unroll
  for (int ti = 0; ti < 4; ++ti) {
    lacc[ti] = f32x4{0, 0, 0, 0};
#pragma unroll
    for (int ct = 0; ct < 4; ++ct) oacc[ti][ct] = f32x4{0, 0, 0, 0};
  }

  __shared__ __align__(16) u16 kls[2][32][64];   // 8 KiB
  __shared__ __align__(16) u16 vls[2][32][64];   // 8 KiB
  constexpr int NIT = (kN / kSplit) / 32;        // 32
  const int s_beg = z * (kN / kSplit);

  // --- staging thread roles (uniform over the loop) ---
  const int srow = tid >> 3, sk8 = tid & 7, skey = srow & 7;
  const u16* ksrc = kb + (size_t)(s_beg + srow) * kD + sk8 * 8;
  u16* kdst = &kls[0][srow][((sk8 ^ skey)) * 8];
  const int sa = sk8 >> 2, sq = sk8 & 3;
  const u16* vsrc = vb + (size_t)(2 * srow + sa) * kN + s_beg + sq * 8;
  u16* vdst = &vls[0][srow][(((sa << 2) | sq) ^ skey) * 8];

  // prologue: load tile 0 into staging regs
  bf16x8 kstg = ldb8(ksrc);
  bf16x8 vstg = ldb8(vsrc);

#pragma unroll 2
  for (int it = 0; it < NIT; ++it) {
    const int cb = (it & 1) * (32 * 64);
    *reinterpret_cast<bf16x8*>(kdst + cb) = kstg;
    *reinterpret_cast<bf16x8*>(vdst + cb) = vstg;
    __syncthreads();
    if (it + 1 < NIT) {
      kstg = ldb8(ksrc + (size_t)(it + 1) * (32 * kD));
      vstg = ldb8(vsrc + (it + 1) * 32);
    }
    const u16* kl = &kls[0][0][0] + cb;
    const u16* vl = &vls[0][0][0] + cb;
    const int kx = (col & 7) * 8;
    const bf16x8 k00 = ldb8(kl + col * 64 + ((quad * 8) ^ kx));
    const bf16x8 k01 = ldb8(kl + col * 64 + ((32 + quad * 8) ^ kx));
    const bf16x8 k10 = ldb8(kl + (col + 16) * 64 + ((quad * 8) ^ kx));
    const bf16x8 k11 = ldb8(kl + (col + 16) * 64 + ((32 + quad * 8) ^ kx));
    bf16x8 vf[4];
    const int vslot = (((col & 1) << 2) | quad) ^ (col >> 1);
#pragma unroll
    for (int ct = 0; ct < 4; ++ct)
      vf[ct] = ldb8(vl + (ct * 8 + (col >> 1)) * 64 + vslot * 8);
#pragma unroll
    for (int ti = 0; ti < 4; ++ti) {
      f32x4 sa0 = {0, 0, 0, 0}, sa1 = {0, 0, 0, 0};
      sa0 = MFMA16x16x32(k00, qf[ti][0], sa0);
      sa0 = MFMA16x16x32(k01, qf[ti][1], sa0);
      sa1 = MFMA16x16x32(k10, qf[ti][0], sa1);
      sa1 = MFMA16x16x32(k11, qf[ti][1], sa1);
      const u32 e00 = __float_as_uint(fast_exp2(sa0[0]));
      const u32 e01 = __float_as_uint(fast_exp2(sa0[1]));
      const u32 e02 = __float_as_uint(fast_exp2(sa0[2]));
      const u32 e03 = __float_as_uint(fast_exp2(sa0[3]));
      const u32 e10 = __float_as_uint(fast_exp2(sa1[0]));
      const u32 e11 = __float_as_uint(fast_exp2(sa1[1]));
      const u32 e12 = __float_as_uint(fast_exp2(sa1[2]));
      const u32 e13 = __float_as_uint(fast_exp2(sa1[3]));
      union { u32 wd[4]; bf16x8 v; } pa;
      pa.wd[0] = __builtin_amdgcn_perm(e01, e00, 0x07060302u);
      pa.wd[1] = __builtin_amdgcn_perm(e03, e02, 0x07060302u);
      pa.wd[2] = __builtin_amdgcn_perm(e11, e10, 0x07060302u);
      pa.wd[3] = __builtin_amdgcn_perm(e13, e12, 0x07060302u);
#pragma unroll
      for (int ct = 0; ct < 4; ++ct)
        oacc[ti][ct] = MFMA16x16x32(pa.v, vf[ct], oacc[ti][ct]);
      lacc[ti] = MFMA16x16x32(pa.v, onesf, lacc[ti]);
    }
  }
  float* po = pO + (size_t)(z * 16 + bh) * kN * kD;
  float* plp = pl + (size_t)(z * 16 + bh) * kN;
#pragma unroll
  for (int ti = 0; ti < 4; ++ti)
#pragma unroll
    for (int r = 0; r < 4; ++r) {
      const int t = t0 + ti * 16 + quad * 4 + r;
#pragma unroll
      for (int ct = 0; ct < 4; ++ct)
        po[(size_t)t * kD + ct * 16 + col] = oacc[ti][ct][r];
      if (col == 0) plp[t] = lacc[ti][r];
    }
}

// ---------------------------------------------------------------------------
// Combine 4 split partials: O = sum_z O_z / sum_z l_z -> ht[b][t][c] bf16.
// ---------------------------------------------------------------------------
__global__ __launch_bounds__(256) void attn_combine(const float* __restrict__ pO,
                                                    const float* __restrict__ pl,
                                                    u16* __restrict__ ht) {
  const int idx = blockIdx.x * 256 + threadIdx.x;   // 16bh * 4096t * 16chunks
  const int c0 = (idx & 15) * 4;
  const int t = (idx >> 4) & (kN - 1);
  const int bh = idx >> 16;
  f32x4 acc = {0, 0, 0, 0};
  float lsum = 0.f;
#pragma unroll
  for (int z = 0; z < kSplit; ++z) {
    const size_t base = ((size_t)(z * 16 + bh) * kN + t);
    acc += *reinterpret_cast<const f32x4*>(pO + base * kD + c0);
    lsum += pl[base];
  }
  const float inv = 1.f / lsum;
  u16x4 pk;
#pragma unroll
  for (int i = 0; i < 4; ++i) pk[i] = f2bf(acc[i] * inv);
  const int b = bh >> 2, head = bh & 3;
  *reinterpret_cast<u16x4*>(ht + (size_t)b * (kN * kC) + (size_t)t * kC +
                            head * kD + c0) = pk;
}

// ---------------------------------------------------------------------------
// Proj GEMM + bias + residual: out fp32 (B,C,H,W). r22: same LDS staging as
// qkv_gemm (A=projw 64x256 tile, B=ht 64x256 tile, coalesced + swizzled).
// Output stores were already coalesced along t.
// ---------------------------------------------------------------------------
__global__ __launch_bounds__(256) void proj_kernel(const u16* __restrict__ projw,
                                                   const float* __restrict__ projb,
                                                   const u16* __restrict__ ht,
                                                   const float* __restrict__ x,
                                                   float* __restrict__ out) {
  const int nblk = blockIdx.x, mblk = blockIdx.y, b = blockIdx.z;
  const int tid = threadIdx.x;
  const int w = tid >> 6, l = tid & 63, quad = l >> 4, col = l & 15;
  const int m0 = mblk * 64 + w * 16;
  const int n0 = nblk * 64;
  __shared__ __align__(16) u16 als[64 * 256];   // 32 KiB
  __shared__ __align__(16) u16 bls[64 * 256];   // 32 KiB
  {
    const u16* asrc = projw + (size_t)(mblk * 64) * kC;
    const u16* bsrc = ht + (size_t)b * (kN * kC) + (size_t)n0 * kC;
#pragma unroll
    for (int p = 0; p < 8; ++p) {
      const int li = p * 256 + tid;
      const int row = li >> 5, ch = li & 31;
      const int sw = (ch ^ (row & 7)) * 8;
      *reinterpret_cast<bf16x8*>(&als[row * 256 + sw]) = ldb8(asrc + li * 8);
      *reinterpret_cast<bf16x8*>(&bls[row * 256 + sw]) = ldb8(bsrc + li * 8);
    }
  }
  __syncthreads();
  f32x4 acc[4] = {{0,0,0,0},{0,0,0,0},{0,0,0,0},{0,0,0,0}};
  const u16* arow = &als[(w * 16 + col) * 256];
  const int kx = col & 7;
#pragma unroll
  for (int ks = 0; ks < 8; ++ks) {
    const bf16x8 af = ldb8(arow + (((ks * 4 + quad) ^ kx)) * 8);
#pragma unroll
    for (int nt = 0; nt < 4; ++nt) {
      const bf16x8 bfr =
          ldb8(&bls[(nt * 16 + col) * 256 + (((ks * 4 + quad) ^ kx)) * 8]);
      acc[nt] = MFMA16x16x32(af, bfr, acc[nt]);
    }
  }
#pragma unroll
  for (int nt = 0; nt < 4; ++nt) {
    const int t = n0 + nt * 16 + col;
#pragma unroll
    for (int r = 0; r < 4; ++r) {
      const int o = m0 + quad * 4 + r;
      const int idx = b * (kC * kN) + o * kN + t;
      out[idx] = acc[nt][r] + projb[o] + x[idx];
    }
  }
}

extern "C" void kernel_launch(void* const* d_in, const int* in_sizes, int n_in,
                              void* d_out, int out_size, void* d_ws, size_t ws_size,
                              hipStream_t stream) {
  const float* x = (const float*)d_in[0];
  const float* gnw = (const float*)d_in[1];
  const float* gnb = (const float*)d_in[2];
  const float* qkvw_f = (const float*)d_in[3];
  const float* qkvb = (const float*)d_in[4];
  const float* projw_f = (const float*)d_in[5];
  const float* projb = (const float*)d_in[6];
  float* out = (float*)d_out;

  char* ws = (char*)d_ws;
  u16* xnT = (u16*)(ws);                      // 8 MiB
  u16* qt = (u16*)(ws + (8u << 20));          // 8 MiB
  u16* kt = (u16*)(ws + (16u << 20));         // 8 MiB
  u16* vv = (u16*)(ws + (24u << 20));         // 8 MiB
  u16* ht = (u16*)(ws + (32u << 20));         // 8 MiB
  u16* qkvw = (u16*)(ws + (40u << 20));       // 384 KiB
  u16* projw = (u16*)(ws + (41u << 20));      // 128 KiB
  float* pO = (float*)(ws + (48u << 20));     // 64 MiB (4 splits)
  float* pl = (float*)(ws + (112u << 20));    // 1 MiB

  convert_bf16<<<dim3(192), dim3(256), 0, stream>>>(qkvw_f, qkvw, 768 * kC);
  convert_bf16<<<dim3(64), dim3(256), 0, stream>>>(projw_f, projw, kC * kC);
  gn_kernel<<<dim3(32, 4), dim3(1024), 0, stream>>>(x, gnw, gnb, xnT);
  qkv_gemm<<<dim3(64, 12, 4), dim3(256), 0, stream>>>(qkvw, qkvb, xnT, qt, kt, vv);
  attn_split<<<dim3(16, 16, kSplit), dim3(256), 0, stream>>>(qt, kt, vv, pO, pl);
  attn_combine<<<dim3(4096), dim3(256), 0, stream>>>(pO, pl, ht);
  proj_kernel<<<dim3(64, 4, 4), dim3(256), 0, stream>>>(projw, projb, ht, x, out);
}

// Round 10
// 192.886 us; speedup vs baseline: 2.1530x; 1.0582x over previous
//
#include <hip/hip_runtime.h>

typedef unsigned short u16;
typedef unsigned int u32;
typedef __bf16 bf16x8 __attribute__((ext_vector_type(8)));
typedef float f32x4 __attribute__((ext_vector_type(4)));
typedef u16 u16x4 __attribute__((ext_vector_type(4)));
typedef u16 u16x8 __attribute__((ext_vector_type(8)));

#define MFMA16x16x32(a, b, c) __builtin_amdgcn_mfma_f32_16x16x32_bf16((a), (b), (c), 0, 0, 0)

static constexpr int kB = 4;
static constexpr int kC = 256;
static constexpr int kN = 4096;     // H*W
static constexpr int kHeads = 4;    // per batch
static constexpr int kD = 64;       // head dim
// r23: kSplit 4->2. Grid 16x16x2 = 512 blocks = exactly 2 blocks/CU x 256 CU
// (single full pass, no tail). Halves pO write + combine read (64->32 MB
// each) and Q refetch (32->16 MB); K/V traffic is kSplit-invariant.
static constexpr int kSplit = 2;
static constexpr float kScale = 0.35355339059327373f;   // 64^-0.25 (K side)
static constexpr float kScaleQ = 0.51006971545f;        // 64^-0.25 * log2(e) (Q side)

__device__ __forceinline__ u16 f2bf(float f) {
  union { float f; u32 i; } v; v.f = f;
  return (u16)((v.i + 0x7fffu + ((v.i >> 16) & 1u)) >> 16);
}
__device__ __forceinline__ bf16x8 ldb8(const u16* p) {
  return *reinterpret_cast<const bf16x8*>(p);
}
// r21 (validated): raw v_exp_f32 (2^x); OCML exp2f carries fixup VALU.
__device__ __forceinline__ float fast_exp2(float x) {
#if __has_builtin(__builtin_amdgcn_exp2f)
  return __builtin_amdgcn_exp2f(x);
#else
  float r;
  asm("v_exp_f32 %0, %1" : "=v"(r) : "v"(x));
  return r;
#endif
}

// ---------------------------------------------------------------------------
// fp32 -> bf16 weight conversion (grid-stride).
// ---------------------------------------------------------------------------
__global__ void convert_bf16(const float* __restrict__ in, u16* __restrict__ out,
                             int n) {
  for (int i = blockIdx.x * blockDim.x + threadIdx.x; i < n;
       i += gridDim.x * blockDim.x)
    out[i] = f2bf(in[i]);
}

// ---------------------------------------------------------------------------
// GroupNorm (validated r4). Writes bf16 transposed xnT[b][t][c].
// ---------------------------------------------------------------------------
__global__ __launch_bounds__(1024) void gn_kernel(const float* __restrict__ x,
                                                  const float* __restrict__ gnw,
                                                  const float* __restrict__ gnb,
                                                  u16* __restrict__ xnT) {
  const int g = blockIdx.x, b = blockIdx.y;
  const int tid = threadIdx.x;
  const float* xb = x + b * (kC * kN) + g * 8 * kN;
  float vals[4][8];
  float s = 0.f, ss = 0.f;
#pragma unroll
  for (int kk = 0; kk < 4; ++kk) {
    const int t = tid + kk * 1024;
#pragma unroll
    for (int c = 0; c < 8; ++c) {
      const float v_ = xb[c * kN + t];
      vals[kk][c] = v_;
      s += v_; ss += v_ * v_;
    }
  }
#pragma unroll
  for (int off = 32; off > 0; off >>= 1) {
    s += __shfl_down(s, off);
    ss += __shfl_down(ss, off);
  }
  __shared__ float rbuf[32];
  const int wid = tid >> 6, lane = tid & 63;
  if (lane == 0) { rbuf[wid] = s; rbuf[16 + wid] = ss; }
  __syncthreads();
  if (tid < 64) {
    float s2 = (lane < 16) ? rbuf[lane] : 0.f;
    float ss2 = (lane < 16) ? rbuf[16 + lane] : 0.f;
#pragma unroll
    for (int off = 8; off > 0; off >>= 1) {
      s2 += __shfl_down(s2, off);
      ss2 += __shfl_down(ss2, off);
    }
    if (lane == 0) { rbuf[0] = s2; rbuf[1] = ss2; }
  }
  __syncthreads();
  const float inv_n = 1.f / 32768.f;
  const float mu = rbuf[0] * inv_n;
  const float var = rbuf[1] * inv_n - mu * mu;
  const float rs = rsqrtf(var + 1e-5f);
  float wv[8], bv[8];
#pragma unroll
  for (int c = 0; c < 8; ++c) {
    const float wgt = gnw[g * 8 + c] * rs;
    wv[c] = wgt;
    bv[c] = gnb[g * 8 + c] - mu * wgt;
  }
  u16* ob = xnT + b * (kN * kC) + g * 8;
#pragma unroll
  for (int kk = 0; kk < 4; ++kk) {
    const int t = tid + kk * 1024;
    u16x8 pk;
#pragma unroll
    for (int c = 0; c < 8; ++c) pk[c] = f2bf(vals[kk][c] * wv[c] + bv[c]);
    *reinterpret_cast<u16x8*>(ob + t * kC) = pk;
  }
}

// ---------------------------------------------------------------------------
// QKV GEMM. r22 (validated): A/B panels staged to LDS with coalesced loads,
// XOR swizzle (chunk c of row r at slot c^(r&7); read at (ks*4+quad)^(col&7)).
// Epilogue: r19 V slot-permutation m = 8*(col>>2)+4*(nt&1)+(col&3) within
// each 32-col block matches attn's in-register P order; Q side folds log2e.
// ---------------------------------------------------------------------------
__global__ __launch_bounds__(256) void qkv_gemm(const u16* __restrict__ qkvw,
                                                const float* __restrict__ qkvb,
                                                const u16* __restrict__ xnT,
                                                u16* __restrict__ qt,
                                                u16* __restrict__ kt,
                                                u16* __restrict__ vv) {
  const int nblk = blockIdx.x, mblk = blockIdx.y, b = blockIdx.z;
  const int tid = threadIdx.x;
  const int w = tid >> 6, l = tid & 63, quad = l >> 4, col = l & 15;
  const int m0 = mblk * 64 + w * 16;
  const int n0 = nblk * 64;
  __shared__ __align__(16) u16 als[64 * 256];   // 32 KiB
  __shared__ __align__(16) u16 bls[64 * 256];   // 32 KiB
  {
    const u16* asrc = qkvw + (size_t)(mblk * 64) * kC;
    const u16* bsrc = xnT + (size_t)b * (kN * kC) + (size_t)n0 * kC;
#pragma unroll
    for (int p = 0; p < 8; ++p) {
      const int li = p * 256 + tid;        // [0,2048)
      const int row = li >> 5, ch = li & 31;
      const int sw = (ch ^ (row & 7)) * 8;
      *reinterpret_cast<bf16x8*>(&als[row * 256 + sw]) = ldb8(asrc + li * 8);
      *reinterpret_cast<bf16x8*>(&bls[row * 256 + sw]) = ldb8(bsrc + li * 8);
    }
  }
  __syncthreads();
  f32x4 acc[4] = {{0,0,0,0},{0,0,0,0},{0,0,0,0},{0,0,0,0}};
  const u16* arow = &als[(w * 16 + col) * 256];
  const int kx = col & 7;
#pragma unroll
  for (int ks = 0; ks < 8; ++ks) {
    const bf16x8 af = ldb8(arow + (((ks * 4 + quad) ^ kx)) * 8);
#pragma unroll
    for (int nt = 0; nt < 4; ++nt) {
      const bf16x8 bfr =
          ldb8(&bls[(nt * 16 + col) * 256 + (((ks * 4 + quad) ^ kx)) * 8]);
      acc[nt] = MFMA16x16x32(af, bfr, acc[nt]);
    }
  }
  const int o_base = m0 + quad * 4;
  const int head = o_base / 192;
  const int rr = o_base % 192;
  const int bh = b * kHeads + head;
  const int seg = rr >> 6;
  const int c0 = rr & 63;
  float bias[4];
#pragma unroll
  for (int r = 0; r < 4; ++r) bias[r] = qkvb[o_base + r];
  const float sc = (seg == 0) ? kScaleQ : kScale;
#pragma unroll
  for (int nt = 0; nt < 4; ++nt) {
    const int t = n0 + nt * 16 + col;
    if (seg == 2) {
      const int tp = n0 + (nt >> 1) * 32 + 8 * (col >> 2) + 4 * (nt & 1) + (col & 3);
#pragma unroll
      for (int r = 0; r < 4; ++r)
        vv[bh * (kD * kN) + (c0 + r) * kN + tp] = f2bf(acc[nt][r] + bias[r]);
    } else {
      u16* dst = (seg == 0 ? qt : kt) + bh * (kN * kD) + t * kD + c0;
      u16x4 pk;
#pragma unroll
      for (int r = 0; r < 4; ++r) pk[r] = f2bf((acc[nt][r] + bias[r]) * sc);
      *reinterpret_cast<u16x4*>(dst) = pk;
    }
  }
}

// ---------------------------------------------------------------------------
// Flash attention, swapped-QK^T register form + cooperative K/V LDS staging.
// r20 (validated): cooperative 8KB K/V staging, XOR-swizzled, dbuf, 1
// barrier/iter -> 140.6->111us. r21 (validated): fast_exp2 + unroll-2 ->
// 111->82.3us (VALU 63->28us). r23: kSplit 2 (see top).
// ---------------------------------------------------------------------------
__global__ __launch_bounds__(256, 2) void attn_split(const u16* __restrict__ qt,
                                                     const u16* __restrict__ kt,
                                                     const u16* __restrict__ vv,
                                                     float* __restrict__ pO,
                                                     float* __restrict__ pl) {
  const int tblk = blockIdx.x, bh = blockIdx.y, z = blockIdx.z;
  const int tid = threadIdx.x;
  const int w = tid >> 6, l = tid & 63, quad = l >> 4, col = l & 15;
  const int t0 = tblk * 256 + w * 64;
  const u16* qb = qt + bh * (kN * kD);
  const u16* kb = kt + bh * (kN * kD);
  const u16* vb = vv + bh * (kD * kN);
  bf16x8 qf[4][2];
#pragma unroll
  for (int ti = 0; ti < 4; ++ti) {
    qf[ti][0] = ldb8(qb + (t0 + ti * 16 + col) * kD + quad * 8);
    qf[ti][1] = ldb8(qb + (t0 + ti * 16 + col) * kD + 32 + quad * 8);
  }
  u16x8 ones_u;
#pragma unroll
  for (int i = 0; i < 8; ++i) ones_u[i] = 0x3f80;  // bf16 1.0
  const bf16x8 onesf = *reinterpret_cast<bf16x8*>(&ones_u);
  f32x4 oacc[4][4];
  f32x4 lacc[4];
#pragma unroll
  for (int ti = 0; ti < 4; ++ti) {
    lacc[ti] = f32x4{0, 0, 0, 0};
#pragma unroll
    for (int ct = 0; ct < 4; ++ct) oacc[ti][ct] = f32x4{0, 0, 0, 0};
  }

  __shared__ __align__(16) u16 kls[2][32][64];   // 8 KiB
  __shared__ __align__(16) u16 vls[2][32][64];   // 8 KiB
  constexpr int NIT = (kN / kSplit) / 32;        // 64
  const int s_beg = z * (kN / kSplit);

  // --- staging thread roles (uniform over the loop) ---
  const int srow = tid >> 3, sk8 = tid & 7, skey = srow & 7;
  const u16* ksrc = kb + (size_t)(s_beg + srow) * kD + sk8 * 8;
  u16* kdst = &kls[0][srow][((sk8 ^ skey)) * 8];
  const int sa = sk8 >> 2, sq = sk8 & 3;
  const u16* vsrc = vb + (size_t)(2 * srow + sa) * kN + s_beg + sq * 8;
  u16* vdst = &vls[0][srow][(((sa << 2) | sq) ^ skey) * 8];

  // prologue: load tile 0 into staging regs
  bf16x8 kstg = ldb8(ksrc);
  bf16x8 vstg = ldb8(vsrc);

#pragma unroll 2
  for (int it = 0; it < NIT; ++it) {
    const int cb = (it & 1) * (32 * 64);
    *reinterpret_cast<bf16x8*>(kdst + cb) = kstg;
    *reinterpret_cast<bf16x8*>(vdst + cb) = vstg;
    __syncthreads();
    if (it + 1 < NIT) {
      kstg = ldb8(ksrc + (size_t)(it + 1) * (32 * kD));
      vstg = ldb8(vsrc + (it + 1) * 32);
    }
    const u16* kl = &kls[0][0][0] + cb;
    const u16* vl = &vls[0][0][0] + cb;
    const int kx = (col & 7) * 8;
    const bf16x8 k00 = ldb8(kl + col * 64 + ((quad * 8) ^ kx));
    const bf16x8 k01 = ldb8(kl + col * 64 + ((32 + quad * 8) ^ kx));
    const bf16x8 k10 = ldb8(kl + (col + 16) * 64 + ((quad * 8) ^ kx));
    const bf16x8 k11 = ldb8(kl + (col + 16) * 64 + ((32 + quad * 8) ^ kx));
    bf16x8 vf[4];
    const int vslot = (((col & 1) << 2) | quad) ^ (col >> 1);
#pragma unroll
    for (int ct = 0; ct < 4; ++ct)
      vf[ct] = ldb8(vl + (ct * 8 + (col >> 1)) * 64 + vslot * 8);
#pragma unroll
    for (int ti = 0; ti < 4; ++ti) {
      f32x4 sa0 = {0, 0, 0, 0}, sa1 = {0, 0, 0, 0};
      sa0 = MFMA16x16x32(k00, qf[ti][0], sa0);
      sa0 = MFMA16x16x32(k01, qf[ti][1], sa0);
      sa1 = MFMA16x16x32(k10, qf[ti][0], sa1);
      sa1 = MFMA16x16x32(k11, qf[ti][1], sa1);
      const u32 e00 = __float_as_uint(fast_exp2(sa0[0]));
      const u32 e01 = __float_as_uint(fast_exp2(sa0[1]));
      const u32 e02 = __float_as_uint(fast_exp2(sa0[2]));
      const u32 e03 = __float_as_uint(fast_exp2(sa0[3]));
      const u32 e10 = __float_as_uint(fast_exp2(sa1[0]));
      const u32 e11 = __float_as_uint(fast_exp2(sa1[1]));
      const u32 e12 = __float_as_uint(fast_exp2(sa1[2]));
      const u32 e13 = __float_as_uint(fast_exp2(sa1[3]));
      union { u32 wd[4]; bf16x8 v; } pa;
      pa.wd[0] = __builtin_amdgcn_perm(e01, e00, 0x07060302u);
      pa.wd[1] = __builtin_amdgcn_perm(e03, e02, 0x07060302u);
      pa.wd[2] = __builtin_amdgcn_perm(e11, e10, 0x07060302u);
      pa.wd[3] = __builtin_amdgcn_perm(e13, e12, 0x07060302u);
#pragma unroll
      for (int ct = 0; ct < 4; ++ct)
        oacc[ti][ct] = MFMA16x16x32(pa.v, vf[ct], oacc[ti][ct]);
      lacc[ti] = MFMA16x16x32(pa.v, onesf, lacc[ti]);
    }
  }
  float* po = pO + (size_t)(z * 16 + bh) * kN * kD;
  float* plp = pl + (size_t)(z * 16 + bh) * kN;
#pragma unroll
  for (int ti = 0; ti < 4; ++ti)
#pragma unroll
    for (int r = 0; r < 4; ++r) {
      const int t = t0 + ti * 16 + quad * 4 + r;
#pragma unroll
      for (int ct = 0; ct < 4; ++ct)
        po[(size_t)t * kD + ct * 16 + col] = oacc[ti][ct][r];
      if (col == 0) plp[t] = lacc[ti][r];
    }
}

// ---------------------------------------------------------------------------
// Combine kSplit split partials: O = sum_z O_z / sum_z l_z -> ht bf16.
// ---------------------------------------------------------------------------
__global__ __launch_bounds__(256) void attn_combine(const float* __restrict__ pO,
                                                    const float* __restrict__ pl,
                                                    u16* __restrict__ ht) {
  const int idx = blockIdx.x * 256 + threadIdx.x;   // 16bh * 4096t * 16chunks
  const int c0 = (idx & 15) * 4;
  const int t = (idx >> 4) & (kN - 1);
  const int bh = idx >> 16;
  f32x4 acc = {0, 0, 0, 0};
  float lsum = 0.f;
#pragma unroll
  for (int z = 0; z < kSplit; ++z) {
    const size_t base = ((size_t)(z * 16 + bh) * kN + t);
    acc += *reinterpret_cast<const f32x4*>(pO + base * kD + c0);
    lsum += pl[base];
  }
  const float inv = 1.f / lsum;
  u16x4 pk;
#pragma unroll
  for (int i = 0; i < 4; ++i) pk[i] = f2bf(acc[i] * inv);
  const int b = bh >> 2, head = bh & 3;
  *reinterpret_cast<u16x4*>(ht + (size_t)b * (kN * kC) + (size_t)t * kC +
                            head * kD + c0) = pk;
}

// ---------------------------------------------------------------------------
// Proj GEMM + bias + residual: out fp32 (B,C,H,W). r22 (validated): LDS
// staging (A=projw 64x256 tile, B=ht 64x256 tile, coalesced + swizzled).
// ---------------------------------------------------------------------------
__global__ __launch_bounds__(256) void proj_kernel(const u16* __restrict__ projw,
                                                   const float* __restrict__ projb,
                                                   const u16* __restrict__ ht,
                                                   const float* __restrict__ x,
                                                   float* __restrict__ out) {
  const int nblk = blockIdx.x, mblk = blockIdx.y, b = blockIdx.z;
  const int tid = threadIdx.x;
  const int w = tid >> 6, l = tid & 63, quad = l >> 4, col = l & 15;
  const int m0 = mblk * 64 + w * 16;
  const int n0 = nblk * 64;
  __shared__ __align__(16) u16 als[64 * 256];   // 32 KiB
  __shared__ __align__(16) u16 bls[64 * 256];   // 32 KiB
  {
    const u16* asrc = projw + (size_t)(mblk * 64) * kC;
    const u16* bsrc = ht + (size_t)b * (kN * kC) + (size_t)n0 * kC;
#pragma unroll
    for (int p = 0; p < 8; ++p) {
      const int li = p * 256 + tid;
      const int row = li >> 5, ch = li & 31;
      const int sw = (ch ^ (row & 7)) * 8;
      *reinterpret_cast<bf16x8*>(&als[row * 256 + sw]) = ldb8(asrc + li * 8);
      *reinterpret_cast<bf16x8*>(&bls[row * 256 + sw]) = ldb8(bsrc + li * 8);
    }
  }
  __syncthreads();
  f32x4 acc[4] = {{0,0,0,0},{0,0,0,0},{0,0,0,0},{0,0,0,0}};
  const u16* arow = &als[(w * 16 + col) * 256];
  const int kx = col & 7;
#pragma unroll
  for (int ks = 0; ks < 8; ++ks) {
    const bf16x8 af = ldb8(arow + (((ks * 4 + quad) ^ kx)) * 8);
#pragma unroll
    for (int nt = 0; nt < 4; ++nt) {
      const bf16x8 bfr =
          ldb8(&bls[(nt * 16 + col) * 256 + (((ks * 4 + quad) ^ kx)) * 8]);
      acc[nt] = MFMA16x16x32(af, bfr, acc[nt]);
    }
  }
#pragma unroll
  for (int nt = 0; nt < 4; ++nt) {
    const int t = n0 + nt * 16 + col;
#pragma unroll
    for (int r = 0; r < 4; ++r) {
      const int o = m0 + quad * 4 + r;
      const int idx = b * (kC * kN) + o * kN + t;
      out[idx] = acc[nt][r] + projb[o] + x[idx];
    }
  }
}

extern "C" void kernel_launch(void* const* d_in, const int* in_sizes, int n_in,
                              void* d_out, int out_size, void* d_ws, size_t ws_size,
                              hipStream_t stream) {
  const float* x = (const float*)d_in[0];
  const float* gnw = (const float*)d_in[1];
  const float* gnb = (const float*)d_in[2];
  const float* qkvw_f = (const float*)d_in[3];
  const float* qkvb = (const float*)d_in[4];
  const float* projw_f = (const float*)d_in[5];
  const float* projb = (const float*)d_in[6];
  float* out = (float*)d_out;

  char* ws = (char*)d_ws;
  u16* xnT = (u16*)(ws);                      // 8 MiB
  u16* qt = (u16*)(ws + (8u << 20));          // 8 MiB
  u16* kt = (u16*)(ws + (16u << 20));         // 8 MiB
  u16* vv = (u16*)(ws + (24u << 20));         // 8 MiB
  u16* ht = (u16*)(ws + (32u << 20));         // 8 MiB
  u16* qkvw = (u16*)(ws + (40u << 20));       // 384 KiB
  u16* projw = (u16*)(ws + (41u << 20));      // 128 KiB
  float* pO = (float*)(ws + (48u << 20));     // 64 MiB region (kSplit<=4)
  float* pl = (float*)(ws + (112u << 20));    // 1 MiB

  convert_bf16<<<dim3(192), dim3(256), 0, stream>>>(qkvw_f, qkvw, 768 * kC);
  convert_bf16<<<dim3(64), dim3(256), 0, stream>>>(projw_f, projw, kC * kC);
  gn_kernel<<<dim3(32, 4), dim3(1024), 0, stream>>>(x, gnw, gnb, xnT);
  qkv_gemm<<<dim3(64, 12, 4), dim3(256), 0, stream>>>(qkvw, qkvb, xnT, qt, kt, vv);
  attn_split<<<dim3(16, 16, kSplit), dim3(256), 0, stream>>>(qt, kt, vv, pO, pl);
  attn_combine<<<dim3(4096), dim3(256), 0, stream>>>(pO, pl, ht);
  proj_kernel<<<dim3(64, 4, 4), dim3(256), 0, stream>>>(projw, projb, ht, x, out);
}

// Round 11
// 188.603 us; speedup vs baseline: 2.2019x; 1.0227x over previous
//
#include <hip/hip_runtime.h>

typedef unsigned short u16;
typedef unsigned int u32;
typedef __bf16 bf16x8 __attribute__((ext_vector_type(8)));
typedef float f32x4 __attribute__((ext_vector_type(4)));
typedef u16 u16x4 __attribute__((ext_vector_type(4)));
typedef u16 u16x8 __attribute__((ext_vector_type(8)));

#define MFMA16x16x32(a, b, c) __builtin_amdgcn_mfma_f32_16x16x32_bf16((a), (b), (c), 0, 0, 0)

static constexpr int kB = 4;
static constexpr int kC = 256;
static constexpr int kN = 4096;     // H*W
static constexpr int kHeads = 4;    // per batch
static constexpr int kD = 64;       // head dim
static constexpr float kScale = 0.35355339059327373f;   // 64^-0.25 (K side)
static constexpr float kScaleQ = 0.51006971545f;        // 64^-0.25 * log2(e) (Q side)

__device__ __forceinline__ u16 f2bf(float f) {
  union { float f; u32 i; } v; v.f = f;
  return (u16)((v.i + 0x7fffu + ((v.i >> 16) & 1u)) >> 16);
}
__device__ __forceinline__ bf16x8 ldb8(const u16* p) {
  return *reinterpret_cast<const bf16x8*>(p);
}
// r21 (validated): raw v_exp_f32 (2^x); OCML exp2f carries fixup VALU.
__device__ __forceinline__ float fast_exp2(float x) {
#if __has_builtin(__builtin_amdgcn_exp2f)
  return __builtin_amdgcn_exp2f(x);
#else
  float r;
  asm("v_exp_f32 %0, %1" : "=v"(r) : "v"(x));
  return r;
#endif
}

// ---------------------------------------------------------------------------
// r24: both weight conversions in ONE launch (grid-stride over concat range).
// ---------------------------------------------------------------------------
__global__ void convert_bf16_2(const float* __restrict__ in1, u16* __restrict__ out1,
                               int n1, const float* __restrict__ in2,
                               u16* __restrict__ out2, int n2) {
  const int total = n1 + n2;
  for (int i = blockIdx.x * blockDim.x + threadIdx.x; i < total;
       i += gridDim.x * blockDim.x) {
    if (i < n1) out1[i] = f2bf(in1[i]);
    else out2[i - n1] = f2bf(in2[i - n1]);
  }
}

// ---------------------------------------------------------------------------
// GroupNorm (validated r4). Writes bf16 transposed xnT[b][t][c].
// ---------------------------------------------------------------------------
__global__ __launch_bounds__(1024) void gn_kernel(const float* __restrict__ x,
                                                  const float* __restrict__ gnw,
                                                  const float* __restrict__ gnb,
                                                  u16* __restrict__ xnT) {
  const int g = blockIdx.x, b = blockIdx.y;
  const int tid = threadIdx.x;
  const float* xb = x + b * (kC * kN) + g * 8 * kN;
  float vals[4][8];
  float s = 0.f, ss = 0.f;
#pragma unroll
  for (int kk = 0; kk < 4; ++kk) {
    const int t = tid + kk * 1024;
#pragma unroll
    for (int c = 0; c < 8; ++c) {
      const float v_ = xb[c * kN + t];
      vals[kk][c] = v_;
      s += v_; ss += v_ * v_;
    }
  }
#pragma unroll
  for (int off = 32; off > 0; off >>= 1) {
    s += __shfl_down(s, off);
    ss += __shfl_down(ss, off);
  }
  __shared__ float rbuf[32];
  const int wid = tid >> 6, lane = tid & 63;
  if (lane == 0) { rbuf[wid] = s; rbuf[16 + wid] = ss; }
  __syncthreads();
  if (tid < 64) {
    float s2 = (lane < 16) ? rbuf[lane] : 0.f;
    float ss2 = (lane < 16) ? rbuf[16 + lane] : 0.f;
#pragma unroll
    for (int off = 8; off > 0; off >>= 1) {
      s2 += __shfl_down(s2, off);
      ss2 += __shfl_down(ss2, off);
    }
    if (lane == 0) { rbuf[0] = s2; rbuf[1] = ss2; }
  }
  __syncthreads();
  const float inv_n = 1.f / 32768.f;
  const float mu = rbuf[0] * inv_n;
  const float var = rbuf[1] * inv_n - mu * mu;
  const float rs = rsqrtf(var + 1e-5f);
  float wv[8], bv[8];
#pragma unroll
  for (int c = 0; c < 8; ++c) {
    const float wgt = gnw[g * 8 + c] * rs;
    wv[c] = wgt;
    bv[c] = gnb[g * 8 + c] - mu * wgt;
  }
  u16* ob = xnT + b * (kN * kC) + g * 8;
#pragma unroll
  for (int kk = 0; kk < 4; ++kk) {
    const int t = tid + kk * 1024;
    u16x8 pk;
#pragma unroll
    for (int c = 0; c < 8; ++c) pk[c] = f2bf(vals[kk][c] * wv[c] + bv[c]);
    *reinterpret_cast<u16x8*>(ob + t * kC) = pk;
  }
}

// ---------------------------------------------------------------------------
// QKV GEMM. r22 (validated): A/B panels staged to LDS with coalesced loads,
// XOR swizzle (chunk c of row r at slot c^(r&7); read at (ks*4+quad)^(col&7)).
// Epilogue: r19 V slot-permutation m = 8*(col>>2)+4*(nt&1)+(col&3) within
// each 32-col block matches attn's in-register P order; Q side folds log2e.
// ---------------------------------------------------------------------------
__global__ __launch_bounds__(256) void qkv_gemm(const u16* __restrict__ qkvw,
                                                const float* __restrict__ qkvb,
                                                const u16* __restrict__ xnT,
                                                u16* __restrict__ qt,
                                                u16* __restrict__ kt,
                                                u16* __restrict__ vv) {
  const int nblk = blockIdx.x, mblk = blockIdx.y, b = blockIdx.z;
  const int tid = threadIdx.x;
  const int w = tid >> 6, l = tid & 63, quad = l >> 4, col = l & 15;
  const int m0 = mblk * 64 + w * 16;
  const int n0 = nblk * 64;
  __shared__ __align__(16) u16 als[64 * 256];   // 32 KiB
  __shared__ __align__(16) u16 bls[64 * 256];   // 32 KiB
  {
    const u16* asrc = qkvw + (size_t)(mblk * 64) * kC;
    const u16* bsrc = xnT + (size_t)b * (kN * kC) + (size_t)n0 * kC;
#pragma unroll
    for (int p = 0; p < 8; ++p) {
      const int li = p * 256 + tid;        // [0,2048)
      const int row = li >> 5, ch = li & 31;
      const int sw = (ch ^ (row & 7)) * 8;
      *reinterpret_cast<bf16x8*>(&als[row * 256 + sw]) = ldb8(asrc + li * 8);
      *reinterpret_cast<bf16x8*>(&bls[row * 256 + sw]) = ldb8(bsrc + li * 8);
    }
  }
  __syncthreads();
  f32x4 acc[4] = {{0,0,0,0},{0,0,0,0},{0,0,0,0},{0,0,0,0}};
  const u16* arow = &als[(w * 16 + col) * 256];
  const int kx = col & 7;
#pragma unroll
  for (int ks = 0; ks < 8; ++ks) {
    const bf16x8 af = ldb8(arow + (((ks * 4 + quad) ^ kx)) * 8);
#pragma unroll
    for (int nt = 0; nt < 4; ++nt) {
      const bf16x8 bfr =
          ldb8(&bls[(nt * 16 + col) * 256 + (((ks * 4 + quad) ^ kx)) * 8]);
      acc[nt] = MFMA16x16x32(af, bfr, acc[nt]);
    }
  }
  const int o_base = m0 + quad * 4;
  const int head = o_base / 192;
  const int rr = o_base % 192;
  const int bh = b * kHeads + head;
  const int seg = rr >> 6;
  const int c0 = rr & 63;
  float bias[4];
#pragma unroll
  for (int r = 0; r < 4; ++r) bias[r] = qkvb[o_base + r];
  const float sc = (seg == 0) ? kScaleQ : kScale;
#pragma unroll
  for (int nt = 0; nt < 4; ++nt) {
    const int t = n0 + nt * 16 + col;
    if (seg == 2) {
      const int tp = n0 + (nt >> 1) * 32 + 8 * (col >> 2) + 4 * (nt & 1) + (col & 3);
#pragma unroll
      for (int r = 0; r < 4; ++r)
        vv[bh * (kD * kN) + (c0 + r) * kN + tp] = f2bf(acc[nt][r] + bias[r]);
    } else {
      u16* dst = (seg == 0 ? qt : kt) + bh * (kN * kD) + t * kD + c0;
      u16x4 pk;
#pragma unroll
      for (int r = 0; r < 4; ++r) pk[r] = f2bf((acc[nt][r] + bias[r]) * sc);
      *reinterpret_cast<u16x4*>(dst) = pk;
    }
  }
}

// ---------------------------------------------------------------------------
// Flash attention, UNSPLIT (r24). 32 q-rows/wave (2 Q-tiles), full-kN sweep,
// 64 s-rows per barrier (two 32-s subtiles per iter -> barrier count stays
// 64, MFMA/iter stays 36). Cooperative K/V staging as validated in r20/r21
// (XOR involutions, dbuf, 1 barrier/iter, fast_exp2, swapped QK^T with
// in-register P, V slot-permutation from qkv_gemm).
// l-division is local: mfma(P, ones) puts l[q] in EVERY column, so each
// lane divides its own oacc rows and writes ht bf16 directly.
// Kills attn_combine + 41MB pO/pl round-trip entirely.
// ---------------------------------------------------------------------------
__global__ __launch_bounds__(256, 2) void attn_split(const u16* __restrict__ qt,
                                                     const u16* __restrict__ kt,
                                                     const u16* __restrict__ vv,
                                                     u16* __restrict__ ht) {
  const int tblk = blockIdx.x, bh = blockIdx.y;
  const int tid = threadIdx.x;
  const int w = tid >> 6, l = tid & 63, quad = l >> 4, col = l & 15;
  const int t0 = tblk * 128 + w * 32;
  const u16* qb = qt + bh * (kN * kD);
  const u16* kb = kt + bh * (kN * kD);
  const u16* vb = vv + bh * (kD * kN);
  bf16x8 qf[2][2];
#pragma unroll
  for (int ti = 0; ti < 2; ++ti) {
    qf[ti][0] = ldb8(qb + (t0 + ti * 16 + col) * kD + quad * 8);
    qf[ti][1] = ldb8(qb + (t0 + ti * 16 + col) * kD + 32 + quad * 8);
  }
  u16x8 ones_u;
#pragma unroll
  for (int i = 0; i < 8; ++i) ones_u[i] = 0x3f80;  // bf16 1.0
  const bf16x8 onesf = *reinterpret_cast<bf16x8*>(&ones_u);
  f32x4 oacc[2][4];
  f32x4 lacc[2];
#pragma unroll
  for (int ti = 0; ti < 2; ++ti) {
    lacc[ti] = f32x4{0, 0, 0, 0};
#pragma unroll
    for (int ct = 0; ct < 4; ++ct) oacc[ti][ct] = f32x4{0, 0, 0, 0};
  }

  __shared__ __align__(16) u16 kls[2][2][32][64];   // 16 KiB: [buf][half]
  __shared__ __align__(16) u16 vls[2][2][32][64];   // 16 KiB
  constexpr int NIT = kN / 64;                       // 64

  // --- staging thread roles (uniform over the loop) ---
  const int srow = tid >> 3, sk8 = tid & 7, skey = srow & 7;
  const u16* ksrc = kb + (size_t)srow * kD + sk8 * 8;
  u16* kdst = &kls[0][0][srow][((sk8 ^ skey)) * 8];
  const int sa = sk8 >> 2, sq = sk8 & 3;
  const u16* vsrc = vb + (size_t)(2 * srow + sa) * kN + sq * 8;
  u16* vdst = &vls[0][0][srow][(((sa << 2) | sq) ^ skey) * 8];

  // prologue: load tile 0 (both 32-s halves)
  bf16x8 kstg0 = ldb8(ksrc);
  bf16x8 kstg1 = ldb8(ksrc + 32 * kD);
  bf16x8 vstg0 = ldb8(vsrc);
  bf16x8 vstg1 = ldb8(vsrc + 32);

#pragma unroll 2
  for (int it = 0; it < NIT; ++it) {
    const int cb = (it & 1) * (2 * 32 * 64);
    *reinterpret_cast<bf16x8*>(kdst + cb) = kstg0;
    *reinterpret_cast<bf16x8*>(kdst + cb + 2048) = kstg1;
    *reinterpret_cast<bf16x8*>(vdst + cb) = vstg0;
    *reinterpret_cast<bf16x8*>(vdst + cb + 2048) = vstg1;
    __syncthreads();
    if (it + 1 < NIT) {
      const size_t sb = (size_t)(it + 1) * 64;
      kstg0 = ldb8(ksrc + sb * kD);
      kstg1 = ldb8(ksrc + (sb + 32) * kD);
      vstg0 = ldb8(vsrc + sb);
      vstg1 = ldb8(vsrc + sb + 32);
    }
    const int kx = (col & 7) * 8;
    const int vslot = (((col & 1) << 2) | quad) ^ (col >> 1);
#pragma unroll
    for (int h = 0; h < 2; ++h) {
      const u16* kl = &kls[0][0][0][0] + cb + h * 2048;
      const u16* vl = &vls[0][0][0][0] + cb + h * 2048;
      const bf16x8 k00 = ldb8(kl + col * 64 + ((quad * 8) ^ kx));
      const bf16x8 k01 = ldb8(kl + col * 64 + ((32 + quad * 8) ^ kx));
      const bf16x8 k10 = ldb8(kl + (col + 16) * 64 + ((quad * 8) ^ kx));
      const bf16x8 k11 = ldb8(kl + (col + 16) * 64 + ((32 + quad * 8) ^ kx));
      bf16x8 vf[4];
#pragma unroll
      for (int ct = 0; ct < 4; ++ct)
        vf[ct] = ldb8(vl + (ct * 8 + (col >> 1)) * 64 + vslot * 8);
#pragma unroll
      for (int ti = 0; ti < 2; ++ti) {
        f32x4 sa0 = {0, 0, 0, 0}, sa1 = {0, 0, 0, 0};
        sa0 = MFMA16x16x32(k00, qf[ti][0], sa0);
        sa0 = MFMA16x16x32(k01, qf[ti][1], sa0);
        sa1 = MFMA16x16x32(k10, qf[ti][0], sa1);
        sa1 = MFMA16x16x32(k11, qf[ti][1], sa1);
        const u32 e00 = __float_as_uint(fast_exp2(sa0[0]));
        const u32 e01 = __float_as_uint(fast_exp2(sa0[1]));
        const u32 e02 = __float_as_uint(fast_exp2(sa0[2]));
        const u32 e03 = __float_as_uint(fast_exp2(sa0[3]));
        const u32 e10 = __float_as_uint(fast_exp2(sa1[0]));
        const u32 e11 = __float_as_uint(fast_exp2(sa1[1]));
        const u32 e12 = __float_as_uint(fast_exp2(sa1[2]));
        const u32 e13 = __float_as_uint(fast_exp2(sa1[3]));
        union { u32 wd[4]; bf16x8 v; } pa;
        pa.wd[0] = __builtin_amdgcn_perm(e01, e00, 0x07060302u);
        pa.wd[1] = __builtin_amdgcn_perm(e03, e02, 0x07060302u);
        pa.wd[2] = __builtin_amdgcn_perm(e11, e10, 0x07060302u);
        pa.wd[3] = __builtin_amdgcn_perm(e13, e12, 0x07060302u);
#pragma unroll
        for (int ct = 0; ct < 4; ++ct)
          oacc[ti][ct] = MFMA16x16x32(pa.v, vf[ct], oacc[ti][ct]);
        lacc[ti] = MFMA16x16x32(pa.v, onesf, lacc[ti]);
      }
    }
  }
  // epilogue: divide by l (every col holds l[q]) and write ht bf16 directly
  const int b = bh >> 2, head = bh & 3;
  u16* hb = ht + (size_t)b * (kN * kC) + head * kD;
#pragma unroll
  for (int ti = 0; ti < 2; ++ti)
#pragma unroll
    for (int r = 0; r < 4; ++r) {
      const int t = t0 + ti * 16 + quad * 4 + r;
      const float inv = 1.f / lacc[ti][r];
#pragma unroll
      for (int ct = 0; ct < 4; ++ct)
        hb[(size_t)t * kC + ct * 16 + col] = f2bf(oacc[ti][ct][r] * inv);
    }
}

// ---------------------------------------------------------------------------
// Proj GEMM + bias + residual: out fp32 (B,C,H,W). r22 (validated): LDS
// staging (A=projw 64x256 tile, B=ht 64x256 tile, coalesced + swizzled).
// ---------------------------------------------------------------------------
__global__ __launch_bounds__(256) void proj_kernel(const u16* __restrict__ projw,
                                                   const float* __restrict__ projb,
                                                   const u16* __restrict__ ht,
                                                   const float* __restrict__ x,
                                                   float* __restrict__ out) {
  const int nblk = blockIdx.x, mblk = blockIdx.y, b = blockIdx.z;
  const int tid = threadIdx.x;
  const int w = tid >> 6, l = tid & 63, quad = l >> 4, col = l & 15;
  const int m0 = mblk * 64 + w * 16;
  const int n0 = nblk * 64;
  __shared__ __align__(16) u16 als[64 * 256];   // 32 KiB
  __shared__ __align__(16) u16 bls[64 * 256];   // 32 KiB
  {
    const u16* asrc = projw + (size_t)(mblk * 64) * kC;
    const u16* bsrc = ht + (size_t)b * (kN * kC) + (size_t)n0 * kC;
#pragma unroll
    for (int p = 0; p < 8; ++p) {
      const int li = p * 256 + tid;
      const int row = li >> 5, ch = li & 31;
      const int sw = (ch ^ (row & 7)) * 8;
      *reinterpret_cast<bf16x8*>(&als[row * 256 + sw]) = ldb8(asrc + li * 8);
      *reinterpret_cast<bf16x8*>(&bls[row * 256 + sw]) = ldb8(bsrc + li * 8);
    }
  }
  __syncthreads();
  f32x4 acc[4] = {{0,0,0,0},{0,0,0,0},{0,0,0,0},{0,0,0,0}};
  const u16* arow = &als[(w * 16 + col) * 256];
  const int kx = col & 7;
#pragma unroll
  for (int ks = 0; ks < 8; ++ks) {
    const bf16x8 af = ldb8(arow + (((ks * 4 + quad) ^ kx)) * 8);
#pragma unroll
    for (int nt = 0; nt < 4; ++nt) {
      const bf16x8 bfr =
          ldb8(&bls[(nt * 16 + col) * 256 + (((ks * 4 + quad) ^ kx)) * 8]);
      acc[nt] = MFMA16x16x32(af, bfr, acc[nt]);
    }
  }
#pragma unroll
  for (int nt = 0; nt < 4; ++nt) {
    const int t = n0 + nt * 16 + col;
#pragma unroll
    for (int r = 0; r < 4; ++r) {
      const int o = m0 + quad * 4 + r;
      const int idx = b * (kC * kN) + o * kN + t;
      out[idx] = acc[nt][r] + projb[o] + x[idx];
    }
  }
}

extern "C" void kernel_launch(void* const* d_in, const int* in_sizes, int n_in,
                              void* d_out, int out_size, void* d_ws, size_t ws_size,
                              hipStream_t stream) {
  const float* x = (const float*)d_in[0];
  const float* gnw = (const float*)d_in[1];
  const float* gnb = (const float*)d_in[2];
  const float* qkvw_f = (const float*)d_in[3];
  const float* qkvb = (const float*)d_in[4];
  const float* projw_f = (const float*)d_in[5];
  const float* projb = (const float*)d_in[6];
  float* out = (float*)d_out;

  char* ws = (char*)d_ws;
  u16* xnT = (u16*)(ws);                      // 8 MiB
  u16* qt = (u16*)(ws + (8u << 20));          // 8 MiB
  u16* kt = (u16*)(ws + (16u << 20));         // 8 MiB
  u16* vv = (u16*)(ws + (24u << 20));         // 8 MiB
  u16* ht = (u16*)(ws + (32u << 20));         // 8 MiB
  u16* qkvw = (u16*)(ws + (40u << 20));       // 384 KiB
  u16* projw = (u16*)(ws + (41u << 20));      // 128 KiB

  convert_bf16_2<<<dim3(256), dim3(256), 0, stream>>>(qkvw_f, qkvw, 768 * kC,
                                                      projw_f, projw, kC * kC);
  gn_kernel<<<dim3(32, 4), dim3(1024), 0, stream>>>(x, gnw, gnb, xnT);
  qkv_gemm<<<dim3(64, 12, 4), dim3(256), 0, stream>>>(qkvw, qkvb, xnT, qt, kt, vv);
  attn_split<<<dim3(32, 16), dim3(256), 0, stream>>>(qt, kt, vv, ht);
  proj_kernel<<<dim3(64, 4, 4), dim3(256), 0, stream>>>(projw, projb, ht, x, out);
}